// Round 1
// 1645.476 us; speedup vs baseline: 1.0473x; 1.0473x over previous
//
#include <hip/hip_runtime.h>
#include <math.h>

#define B_ 2
#define L_ 1024
#define D_ 768
#define NL_ 8
#define DI_ 1536
#define NS_ 16
#define DR_ 48
#define KC_ 4
#define EPS_ 1e-5f
#define M_ (B_*L_)   // 2048 rows
#define NC_ 64       // scan chunks (thread-per-channel layout)
#define T_ 16        // chunk length (NC_*T_ == L_)
#define KS_ 16       // x_proj split-K factor
#define KCH_ (DI_/KS_)   // 96 per split

typedef short bf16x8 __attribute__((ext_vector_type(8)));
typedef float f32x4  __attribute__((ext_vector_type(4)));

// ---------------- fp32 -> bf16 (RNE) ---------------------------------------
__device__ __forceinline__ unsigned short f2bf(float f) {
    union { float f; unsigned int u; } v; v.f = f;
    unsigned int u = v.u;
    u += 0x7fffu + ((u >> 16) & 1u);
    return (unsigned short)(u >> 16);
}

__device__ __forceinline__ unsigned int pk2(float a, float b) {
    return (unsigned int)f2bf(a) | ((unsigned int)f2bf(b) << 16);
}

// async global->LDS, 16B per lane; LDS dest must be wave-uniform base + lane*16
__device__ __forceinline__ void gload16(const void* g, void* l) {
    __builtin_amdgcn_global_load_lds(
        (const __attribute__((address_space(1))) void*)g,
        (__attribute__((address_space(3))) void*)l, 16, 0, 0);
}

// one dispatch: all weight converts + negA + init, vectorized 8 elems/thread
__global__ void prep_kernel(const float* __restrict__ wi, unsigned short* __restrict__ wi_bf, int n0,
                            const float* __restrict__ wo, unsigned short* __restrict__ wo_bf, int n1,
                            const float* __restrict__ wx, unsigned short* __restrict__ wx_bf, int n2,
                            const float* __restrict__ A_log, float* __restrict__ negA, int n3,
                            const float* __restrict__ x, float* __restrict__ xcur,
                            float* __restrict__ res, int n4) {
    int i = (blockIdx.x * 256 + threadIdx.x) * 8;
    if (i < n0) {
        float4 a = *(const float4*)&wi[i], b = *(const float4*)&wi[i + 4];
        uint4 o = {pk2(a.x, a.y), pk2(a.z, a.w), pk2(b.x, b.y), pk2(b.z, b.w)};
        *(uint4*)&wi_bf[i] = o;
    }
    if (i < n1) {
        float4 a = *(const float4*)&wo[i], b = *(const float4*)&wo[i + 4];
        uint4 o = {pk2(a.x, a.y), pk2(a.z, a.w), pk2(b.x, b.y), pk2(b.z, b.w)};
        *(uint4*)&wo_bf[i] = o;
    }
    if (i < n2) {
        float4 a = *(const float4*)&wx[i], b = *(const float4*)&wx[i + 4];
        uint4 o = {pk2(a.x, a.y), pk2(a.z, a.w), pk2(b.x, b.y), pk2(b.z, b.w)};
        *(uint4*)&wx_bf[i] = o;
    }
    if (i < n3) {
        float4 a = *(const float4*)&A_log[i], b = *(const float4*)&A_log[i + 4];
        float4 ra = make_float4(-__expf(a.x), -__expf(a.y), -__expf(a.z), -__expf(a.w));
        float4 rb = make_float4(-__expf(b.x), -__expf(b.y), -__expf(b.z), -__expf(b.w));
        *(float4*)&negA[i] = ra;
        *(float4*)&negA[i + 4] = rb;
    }
    if (i < n4) {
        float4 a = *(const float4*)&x[i], b = *(const float4*)&x[i + 4];
        *(float4*)&xcur[i] = a;
        *(float4*)&xcur[i + 4] = b;
        float4 z = make_float4(0.f, 0.f, 0.f, 0.f);
        *(float4*)&res[i] = z;
        *(float4*)&res[i + 4] = z;
    }
}

// ---------------- block reduction helper (256 threads = 4 waves) ------------
__device__ __forceinline__ float block_sum256(float v) {
    __shared__ float sb[4];
    #pragma unroll
    for (int o = 32; o > 0; o >>= 1) v += __shfl_down(v, o);
    if ((threadIdx.x & 63) == 0) sb[threadIdx.x >> 6] = v;
    __syncthreads();
    float r = sb[0] + sb[1] + sb[2] + sb[3];
    __syncthreads();
    return r;
}

// ---------------- fused residual-accumulate + LayerNorm (bf16 out) ----------
__global__ __launch_bounds__(256) void ln_res_kernel(
    const float* __restrict__ xcur, float* __restrict__ res,
    const float* __restrict__ w, const float* __restrict__ b,
    unsigned short* __restrict__ xn) {
    int row = blockIdx.x;
    int t = threadIdx.x;
    size_t base = (size_t)row * D_;
    float v0 = xcur[base + t];
    float v1 = xcur[base + t + 256];
    float v2 = xcur[base + t + 512];
    res[base + t]       += v0;
    res[base + t + 256] += v1;
    res[base + t + 512] += v2;
    float mu = block_sum256(v0 + v1 + v2) * (1.0f / D_);
    float d0 = v0 - mu, d1 = v1 - mu, d2 = v2 - mu;
    float var = block_sum256(d0 * d0 + d1 * d1 + d2 * d2) * (1.0f / D_);
    float rs = rsqrtf(var + EPS_);
    xn[base + t]       = f2bf(d0 * rs * w[t]       + b[t]);
    xn[base + t + 256] = f2bf(d1 * rs * w[t + 256] + b[t + 256]);
    xn[base + t + 512] = f2bf(d2 * rs * w[t + 512] + b[t + 512]);
}

// ---------------- final LN: out = LN(xcur + res) ----------------------------
__global__ __launch_bounds__(256) void final_ln_kernel(
    const float* __restrict__ xcur, const float* __restrict__ res,
    const float* __restrict__ w, const float* __restrict__ b,
    float* __restrict__ out) {
    int row = blockIdx.x;
    int t = threadIdx.x;
    size_t base = (size_t)row * D_;
    float v0 = xcur[base + t]       + res[base + t];
    float v1 = xcur[base + t + 256] + res[base + t + 256];
    float v2 = xcur[base + t + 512] + res[base + t + 512];
    float mu = block_sum256(v0 + v1 + v2) * (1.0f / D_);
    float d0 = v0 - mu, d1 = v1 - mu, d2 = v2 - mu;
    float var = block_sum256(d0 * d0 + d1 * d1 + d2 * d2) * (1.0f / D_);
    float rs = rsqrtf(var + EPS_);
    out[base + t]       = d0 * rs * w[t]       + b[t];
    out[base + t + 256] = d1 * rs * w[t + 256] + b[t + 256];
    out[base + t + 512] = d2 * rs * w[t + 512] + b[t + 512];
}

// ---------------- bf16 MFMA GEMM: C[M,N] = A[M,K] * W[N,K]^T ---------------
// 2x2 wave layout; staging via async global_load_lds (width 16).
template <int BM, int BN>
__global__ __launch_bounds__(256) void gemm_bf16_t(
    const unsigned short* __restrict__ A,   // M x K bf16 row-major
    const unsigned short* __restrict__ W,   // N x K bf16 row-major
    float* __restrict__ C, int M, int N, int K) {
    constexpr int FM = BM / 32;             // 16x16 frags per wave (rows)
    constexpr int FN = BN / 32;             // 16x16 frags per wave (cols)
    constexpr int NLD = (BM + BN) / 64;     // 16B chunks per thread per k-tile
    __shared__ unsigned short sA[BM * 32];
    __shared__ unsigned short sW[BN * 32];
    int bm = blockIdx.y * BM, bn = blockIdx.x * BN;
    int tid = threadIdx.x;
    int wave = tid >> 6, lane = tid & 63;
    int wrow = (wave & 1) * (BM / 2), wcol = (wave >> 1) * (BN / 2);
    int quad = lane >> 4, r16 = lane & 15;
    f32x4 acc[FM][FN];
    #pragma unroll
    for (int i = 0; i < FM; i++)
        #pragma unroll
        for (int j = 0; j < FN; j++)
            acc[i][j] = (f32x4){0.f, 0.f, 0.f, 0.f};

    for (int k0 = 0; k0 < K; k0 += 32) {
        #pragma unroll
        for (int r = 0; r < NLD; r++) {
            if (r < BM / 64) {            // uniform per r (folds at unroll)
                int j = r * 256 + tid;    // chunk idx in sA; byte off = j*16
                gload16(&A[(size_t)(bm + (j >> 2)) * K + k0 + (j & 3) * 8],
                        &sA[(r * 256 + wave * 64) * 8]);
            } else {
                int j = (r - BM / 64) * 256 + tid;
                gload16(&W[(size_t)(bn + (j >> 2)) * K + k0 + (j & 3) * 8],
                        &sW[((r - BM / 64) * 256 + wave * 64) * 8]);
            }
        }
        __syncthreads();
        bf16x8 af[FM], wf[FN];
        #pragma unroll
        for (int i = 0; i < FM; i++)
            af[i] = *(const bf16x8*)&sA[(wrow + i * 16 + r16) * 32 + quad * 8];
        #pragma unroll
        for (int j = 0; j < FN; j++)
            wf[j] = *(const bf16x8*)&sW[(wcol + j * 16 + r16) * 32 + quad * 8];
        #pragma unroll
        for (int i = 0; i < FM; i++)
            #pragma unroll
            for (int j = 0; j < FN; j++)
                acc[i][j] = __builtin_amdgcn_mfma_f32_16x16x32_bf16(
                    af[i], wf[j], acc[i][j], 0, 0, 0);
        __syncthreads();
    }
    #pragma unroll
    for (int i = 0; i < FM; i++) {
        #pragma unroll
        for (int j = 0; j < FN; j++) {
            int col = bn + wcol + j * 16 + r16;
            #pragma unroll
            for (int reg = 0; reg < 4; reg++) {
                int row = bm + wrow + i * 16 + quad * 4 + reg;
                C[(size_t)row * N + col] = acc[i][j][reg];
            }
        }
    }
}

// ---------------- x_proj GEMM: Pb[ks][M][80] partials, bf16 MFMA, split-K ---
__global__ __launch_bounds__(256) void xproj_gemm_kernel(
    const unsigned short* __restrict__ A,   // M x DI bf16 (xcb)
    const unsigned short* __restrict__ W,   // 80 x DI bf16
    float* __restrict__ Pb) {               // KS x M x 80 partials
    __shared__ unsigned short sA[64 * 32];
    __shared__ unsigned short sW[80 * 32];
    int ks = blockIdx.x;
    int bm = blockIdx.y * 64;
    int tid = threadIdx.x;
    int wave = tid >> 6, lane = tid & 63;
    int quad = lane >> 4, r16 = lane & 15;
    f32x4 acc[5];
    #pragma unroll
    for (int j = 0; j < 5; j++) acc[j] = (f32x4){0.f, 0.f, 0.f, 0.f};
    int k0base = ks * KCH_;
    for (int kc = 0; kc < KCH_; kc += 32) {
        int k0 = k0base + kc;
        gload16(&A[(size_t)(bm + (tid >> 2)) * DI_ + k0 + (tid & 3) * 8],
                &sA[wave * 512]);
        gload16(&W[(size_t)(tid >> 2) * DI_ + k0 + (tid & 3) * 8],
                &sW[wave * 512]);
        if (tid < 64) {
            int c = 256 + tid;
            gload16(&W[(size_t)(c >> 2) * DI_ + k0 + (c & 3) * 8],
                    &sW[2048]);
        }
        __syncthreads();
        bf16x8 af = *(const bf16x8*)&sA[(wave * 16 + r16) * 32 + quad * 8];
        #pragma unroll
        for (int j = 0; j < 5; j++) {
            bf16x8 wf = *(const bf16x8*)&sW[(j * 16 + r16) * 32 + quad * 8];
            acc[j] = __builtin_amdgcn_mfma_f32_16x16x32_bf16(af, wf, acc[j], 0, 0, 0);
        }
        __syncthreads();
    }
    #pragma unroll
    for (int j = 0; j < 5; j++) {
        int col = j * 16 + r16;
        #pragma unroll
        for (int reg = 0; reg < 4; reg++) {
            int row = bm + wave * 16 + quad * 4 + reg;
            Pb[((size_t)ks * M_ + row) * 80 + col] = acc[j][reg];
        }
    }
}

// reduce split-K partials; scatter into dbcdt (M x 48) and packed BC (M x 16 float2)
__global__ void xproj_reduce_kernel(const float* __restrict__ Pb,
                                    float* __restrict__ dbcdt,
                                    float* __restrict__ bcp) {
    int i = blockIdx.x * 256 + threadIdx.x;   // over M_*80
    float s = 0.f;
    #pragma unroll
    for (int ks = 0; ks < KS_; ks++) s += Pb[(size_t)ks * (M_ * 80) + i];
    int m = i / 80, col = i % 80;
    if (col < DR_) {
        dbcdt[m * DR_ + col] = s;
    } else if (col < DR_ + NS_) {
        bcp[m * 32 + 2 * (col - DR_)] = s;         // B_n
    } else {
        bcp[m * 32 + 2 * (col - DR_ - NS_) + 1] = s; // C_n
    }
}

// ---------------- dt GEMM (fp32, K=48): writes dt into dtxc[...].x ----------
__global__ __launch_bounds__(256) void dt_gemm_kernel(
    const float* __restrict__ A,          // M x 48 (dbcdt)
    const float* __restrict__ W,          // DI x 48 (dt_w)
    const float* __restrict__ bias,       // DI (dt_b)
    float* __restrict__ dtxc) {           // M x DI x 2, writes slot .x
    const int BM = 64, BN = 64, BK = 16;
    __shared__ float sA[BK][BM + 1];
    __shared__ float sW[BK][BN + 1];
    int bm = blockIdx.y * BM, bn = blockIdx.x * BN;
    int tid = threadIdx.x;
    int tx = tid & 15, ty = tid >> 4;
    float acc[4][4] = {};
    for (int k0 = 0; k0 < DR_; k0 += BK) {
        #pragma unroll
        for (int r = 0; r < 4; r++) {
            int j = tid + 256 * r;
            int k = j & 15, m = j >> 4;
            sA[k][m] = A[(size_t)(bm + m) * DR_ + k0 + k];
        }
        #pragma unroll
        for (int r = 0; r < 4; r++) {
            int j = tid + 256 * r;
            int k = j & 15, n = j >> 4;
            sW[k][n] = W[(size_t)(bn + n) * DR_ + k0 + k];
        }
        __syncthreads();
        #pragma unroll
        for (int k = 0; k < BK; k++) {
            float a[4], w[4];
            #pragma unroll
            for (int i = 0; i < 4; i++) a[i] = sA[k][ty * 4 + i];
            #pragma unroll
            for (int j = 0; j < 4; j++) w[j] = sW[k][tx * 4 + j];
            #pragma unroll
            for (int i = 0; i < 4; i++)
                #pragma unroll
                for (int j = 0; j < 4; j++)
                    acc[i][j] += a[i] * w[j];
        }
        __syncthreads();
    }
    #pragma unroll
    for (int i = 0; i < 4; i++) {
        int m = bm + ty * 4 + i;
        #pragma unroll
        for (int j = 0; j < 4; j++) {
            int n = bn + tx * 4 + j;
            float v = acc[i][j] + bias[n];
            v = (v > 20.f) ? v : log1pf(__expf(v));
            dtxc[((size_t)m * DI_ + n) * 2] = v;   // .x slot
        }
    }
}

// ---------------- causal depthwise conv (K=4) + bias + SiLU -----------------
__global__ void conv_silu_kernel(const float* __restrict__ xz,
                                 const float* __restrict__ cw,
                                 const float* __restrict__ cb,
                                 float* __restrict__ dtxc,
                                 unsigned short* __restrict__ xcb) {
    int idx = blockIdx.x * blockDim.x + threadIdx.x;   // over B*L*DI
    if (idx >= B_ * L_ * DI_) return;
    int d = idx % DI_;
    int t = (idx / DI_) % L_;
    int b = idx / (DI_ * L_);
    float acc = cb[d];
    #pragma unroll
    for (int k = 0; k < KC_; k++) {
        int tt = t + k - (KC_ - 1);
        if (tt >= 0)
            acc += xz[((size_t)(b * L_ + tt)) * (2 * DI_) + d] * cw[d * KC_ + k];
    }
    float v = acc / (1.0f + __expf(-acc));
    dtxc[(size_t)idx * 2 + 1] = v;   // .y slot
    xcb[idx] = f2bf(v);
}

// ---------------- scan pass 1: thread-per-channel, h[16] in registers -------
__global__ __launch_bounds__(256) void scan_chunk_kernel(
    const float2* __restrict__ dtxc,   // (B*L, DI) {dt, xc}
    const float4* __restrict__ bcp4,   // (B*L, 8) {B0,C0,B1,C1}x4 view
    const float* __restrict__ negA,    // (DI, NS) this layer
    float* __restrict__ Pbuf, float* __restrict__ Sbuf,
    float2* __restrict__ ylcd) {       // (B*L, DI) {y_local, cumdt}
    const int NDB = DI_ / 256;         // 6 d-blocks
    int bx = blockIdx.x;
    int dblk = bx % NDB;
    int c = (bx / NDB) % NC_;
    int b = bx / (NDB * NC_);
    int d = dblk * 256 + threadIdx.x;

    float A[NS_];
    #pragma unroll
    for (int n = 0; n < NS_; n++) A[n] = negA[(size_t)d * NS_ + n];
    float h[NS_];
    #pragma unroll
    for (int n = 0; n < NS_; n++) h[n] = 0.f;
    float sd = 0.f;

    size_t btbase = (size_t)(b * L_ + c * T_);
    const float2* pdx = dtxc + btbase * DI_ + d;
    const float4* pbc = bcp4 + btbase * 8;
    float2*       pyl = ylcd + btbase * DI_ + d;

    #pragma unroll
    for (int t = 0; t < T_; t++) {
        float2 dx = pdx[(size_t)t * DI_];
        float dt = dx.x;
        float u = dt * dx.y;
        sd += dt;
        float y = 0.f;
        #pragma unroll
        for (int q = 0; q < 8; q++) {
            float4 v = pbc[t * 8 + q];     // {B_2q, C_2q, B_2q+1, C_2q+1}
            float e0 = __expf(dt * A[2 * q]);
            h[2 * q] = fmaf(e0, h[2 * q], u * v.x);
            y = fmaf(v.y, h[2 * q], y);
            float e1 = __expf(dt * A[2 * q + 1]);
            h[2 * q + 1] = fmaf(e1, h[2 * q + 1], u * v.z);
            y = fmaf(v.w, h[2 * q + 1], y);
        }
        pyl[(size_t)t * DI_] = make_float2(y, sd);
    }

    size_t o = (((size_t)b * NC_ + c) * DI_ + d) * NS_;
    #pragma unroll
    for (int n = 0; n < NS_; n++) {
        Pbuf[o + n] = __expf(A[n] * sd);
        Sbuf[o + n] = h[n];
    }
}

// ---------------- scan pass 2: sequential combine over chunks ---------------
// 1-ahead register prefetch breaks the load->fma dependent chain.
__global__ __launch_bounds__(256) void scan_part2(
    const float* __restrict__ P, const float* __restrict__ S,
    float* __restrict__ hin) {
    int i = blockIdx.x * 256 + threadIdx.x;   // over B*DI*NS
    int b = i / (DI_ * NS_);
    int rem = i % (DI_ * NS_);
    const size_t str = (size_t)DI_ * NS_;
    size_t o = (size_t)b * NC_ * str + rem;
    float h = 0.f;
    float p = P[o], s = S[o];
    #pragma unroll 4
    for (int c = 0; c < NC_ - 1; c++) {
        float pn = P[o + str];
        float sn = S[o + str];
        hin[o] = h;
        h = fmaf(p, h, s);
        p = pn; s = sn;
        o += str;
    }
    hin[o] = h;
}

// ---------------- scan pass 3: PARALLEL finalize ----------------------------
__global__ __launch_bounds__(256) void scan_finalize_kernel(
    const float2* __restrict__ ylcd, const float2* __restrict__ dtxc,
    const float* __restrict__ bcp,    // (B*L, 32) interleaved {B,C}
    const float* __restrict__ xz, const float* __restrict__ negA,
    const float* __restrict__ Dp, const float* __restrict__ hin,
    unsigned short* __restrict__ yg) {
    int idx = blockIdx.x * 256 + threadIdx.x;   // over B*L*DI, d fastest
    int d = idx % DI_;
    int bt = idx / DI_;
    int b = bt / L_;
    int t = bt % L_;
    int c = t / T_;
    float2 yl = ylcd[idx];
    float cd = yl.y;
    const float4* hr4 = (const float4*)(hin + (((size_t)b * NC_ + c) * DI_ + d) * NS_);
    const float4* Ar4 = (const float4*)(negA + (size_t)d * NS_);
    const float4* bc4 = (const float4*)(bcp + (size_t)bt * 32);
    float corr = 0.f;
    #pragma unroll
    for (int q = 0; q < 4; q++) {
        float4 hv = hr4[q];
        float4 av = Ar4[q];
        float4 c0 = bc4[2 * q];       // {B,C,B,C}
        float4 c1 = bc4[2 * q + 1];
        corr += c0.y * __expf(av.x * cd) * hv.x;
        corr += c0.w * __expf(av.y * cd) * hv.y;
        corr += c1.y * __expf(av.z * cd) * hv.z;
        corr += c1.w * __expf(av.w * cd) * hv.w;
    }
    float xv = dtxc[idx].y;
    float zv = xz[(size_t)bt * (2 * DI_) + DI_ + d];
    float yy = yl.x + corr + xv * Dp[d];
    yy *= zv / (1.0f + __expf(-zv));
    yg[idx] = f2bf(yy);
}

extern "C" void kernel_launch(void* const* d_in, const int* in_sizes, int n_in,
                              void* d_out, int out_size, void* d_ws, size_t ws_size,
                              hipStream_t stream) {
    const float* x        = (const float*)d_in[0];
    const float* ln_w     = (const float*)d_in[1];
    const float* ln_b     = (const float*)d_in[2];
    const float* in_proj  = (const float*)d_in[3];
    const float* conv_w   = (const float*)d_in[4];
    const float* conv_b   = (const float*)d_in[5];
    const float* x_proj   = (const float*)d_in[6];
    const float* dt_w     = (const float*)d_in[7];
    const float* dt_b     = (const float*)d_in[8];
    const float* A_log    = (const float*)d_in[9];
    const float* D_skip   = (const float*)d_in[10];
    const float* out_proj = (const float*)d_in[11];
    const float* fn_w     = (const float*)d_in[12];
    const float* fn_b     = (const float*)d_in[13];
    float* out = (float*)d_out;

    char* p = (char*)d_ws;
    auto alloc = [&](size_t bytes) {
        char* r = p;
        p += (bytes + 255) & ~(size_t)255;
        return (void*)r;
    };
    float* xcur = (float*)alloc((size_t)M_ * D_ * 4);
    float* res  = (float*)alloc((size_t)M_ * D_ * 4);
    unsigned short* xn = (unsigned short*)alloc((size_t)M_ * D_ * 2);
    float* xz   = (float*)alloc((size_t)M_ * 2 * DI_ * 4);
    unsigned short* xcb = (unsigned short*)alloc((size_t)M_ * DI_ * 2);
    float* dtxc = (float*)alloc((size_t)M_ * DI_ * 2 * 4);   // {dt, xc} pairs
    float* dbcdt = (float*)alloc((size_t)M_ * DR_ * 4);
    float* bcp  = (float*)alloc((size_t)M_ * 32 * 4);        // {B,C} pairs x 16
    unsigned short* yg = (unsigned short*)alloc((size_t)M_ * DI_ * 2);
    float* Pbuf = (float*)alloc((size_t)B_ * NC_ * DI_ * NS_ * 4);   // 12.6 MB
    float* Sbuf = (float*)alloc((size_t)B_ * NC_ * DI_ * NS_ * 4);
    float* hin  = (float*)alloc((size_t)B_ * NC_ * DI_ * NS_ * 4);
    float* ylcd = (float*)alloc((size_t)M_ * DI_ * 2 * 4);   // {y_local, cumdt}
    float* Pb   = (float*)alloc((size_t)KS_ * M_ * 80 * 4);
    float* negA = (float*)alloc((size_t)NL_ * DI_ * NS_ * 4);
    const size_t n_wi = (size_t)NL_ * 2 * DI_ * D_;   // 18.87M
    const size_t n_wo = (size_t)NL_ * D_ * DI_;       // 9.44M
    const size_t n_wx = (size_t)NL_ * 80 * DI_;       // 0.98M
    unsigned short* wi_bf = (unsigned short*)alloc(n_wi * 2);
    unsigned short* wo_bf = (unsigned short*)alloc(n_wo * 2);
    unsigned short* wx_bf = (unsigned short*)alloc(n_wx * 2);

    // fused prep: weight converts + negA + init (8 elems/thread, vectorized)
    prep_kernel<<<(int)((n_wi / 8 + 255) / 256), 256, 0, stream>>>(
        in_proj, wi_bf, (int)n_wi,
        out_proj, wo_bf, (int)n_wo,
        x_proj, wx_bf, (int)n_wx,
        A_log, negA, NL_ * DI_ * NS_,
        x, xcur, res, M_ * D_);

    for (int l = 0; l < NL_; l++) {
        const float* negA_l = negA + (size_t)l * DI_ * NS_;

        ln_res_kernel<<<M_, 256, 0, stream>>>(
            xcur, res, ln_w + l * D_, ln_b + l * D_, xn);

        // xz = xn @ Wi^T   (M=2048, N=3072, K=768)  bf16 MFMA, 128x128 tiles
        gemm_bf16_t<128, 128><<<dim3((2 * DI_) / 128, M_ / 128), 256, 0, stream>>>(
            xn, wi_bf + (size_t)l * 2 * DI_ * D_, xz, M_, 2 * DI_, D_);

        conv_silu_kernel<<<(B_ * L_ * DI_ + 255) / 256, 256, 0, stream>>>(
            xz, conv_w + l * DI_ * KC_, conv_b + l * DI_, dtxc, xcb);

        // dbc = xcb @ Wx^T  (M=2048, N=80, K=1536)  bf16 MFMA split-K
        xproj_gemm_kernel<<<dim3(KS_, M_ / 64), 256, 0, stream>>>(
            xcb, wx_bf + (size_t)l * 80 * DI_, Pb);
        xproj_reduce_kernel<<<(M_ * 80) / 256, 256, 0, stream>>>(Pb, dbcdt, bcp);

        // dt = softplus(dbcdt @ Wdt^T + bdt) -> dtxc.x  (M=2048, N=1536, K=48)
        dt_gemm_kernel<<<dim3(DI_ / 64, M_ / 64), 256, 0, stream>>>(
            dbcdt, dt_w + (size_t)l * DI_ * DR_, dt_b + l * DI_, dtxc);

        // selective scan: thread-per-channel local scan + combine + finalize
        scan_chunk_kernel<<<B_ * NC_ * (DI_ / 256), 256, 0, stream>>>(
            (const float2*)dtxc, (const float4*)bcp, negA_l,
            Pbuf, Sbuf, (float2*)ylcd);
        scan_part2<<<(B_ * DI_ * NS_) / 256, 256, 0, stream>>>(Pbuf, Sbuf, hin);
        scan_finalize_kernel<<<(M_ * DI_) / 256, 256, 0, stream>>>(
            (const float2*)ylcd, (const float2*)dtxc, bcp, xz, negA_l,
            D_skip + (size_t)l * DI_, hin, yg);

        // xcur = yg @ Wo^T  (M=2048, N=768, K=1536)  bf16 MFMA, 128x64 tiles
        // 128x64 -> grid 192 blocks (was 96): CU fill 37%->75%
        gemm_bf16_t<128, 64><<<dim3(D_ / 64, M_ / 128), 256, 0, stream>>>(
            yg, wo_bf + (size_t)l * D_ * DI_, xcur, M_, D_, DI_);
    }

    final_ln_kernel<<<M_, 256, 0, stream>>>(xcur, res, fn_w, fn_b, out);
}

// Round 2
// 1641.524 us; speedup vs baseline: 1.0499x; 1.0024x over previous
//
#include <hip/hip_runtime.h>
#include <math.h>

#define B_ 2
#define L_ 1024
#define D_ 768
#define NL_ 8
#define DI_ 1536
#define NS_ 16
#define DR_ 48
#define KC_ 4
#define EPS_ 1e-5f
#define M_ (B_*L_)   // 2048 rows
#define NC_ 64       // scan chunks (thread-per-channel layout)
#define T_ 16        // chunk length (NC_*T_ == L_)
#define KS_ 16       // x_proj split-K factor
#define KCH_ (DI_/KS_)   // 96 per split
#define KDT_ 64          // dt GEMM padded K (48 -> 64)

typedef short bf16x8 __attribute__((ext_vector_type(8)));
typedef float f32x4  __attribute__((ext_vector_type(4)));

// ---------------- fp32 -> bf16 (RNE) ---------------------------------------
__device__ __forceinline__ unsigned short f2bf(float f) {
    union { float f; unsigned int u; } v; v.f = f;
    unsigned int u = v.u;
    u += 0x7fffu + ((u >> 16) & 1u);
    return (unsigned short)(u >> 16);
}

__device__ __forceinline__ unsigned int pk2(float a, float b) {
    return (unsigned int)f2bf(a) | ((unsigned int)f2bf(b) << 16);
}

// async global->LDS, 16B per lane; LDS dest must be wave-uniform base + lane*16
__device__ __forceinline__ void gload16(const void* g, void* l) {
    __builtin_amdgcn_global_load_lds(
        (const __attribute__((address_space(1))) void*)g,
        (__attribute__((address_space(3))) void*)l, 16, 0, 0);
}

// one dispatch: all weight converts + negA + init, vectorized 8 elems/thread
__global__ void prep_kernel(const float* __restrict__ wi, unsigned short* __restrict__ wi_bf, int n0,
                            const float* __restrict__ wo, unsigned short* __restrict__ wo_bf, int n1,
                            const float* __restrict__ wx, unsigned short* __restrict__ wx_bf, int n2,
                            const float* __restrict__ A_log, float* __restrict__ negA, int n3,
                            const float* __restrict__ x, float* __restrict__ xcur,
                            float* __restrict__ res, int n4,
                            const float* __restrict__ wdt, unsigned short* __restrict__ wdt_bf, int n5,
                            unsigned short* __restrict__ dbc_bf, int n6) {
    int i = (blockIdx.x * 256 + threadIdx.x) * 8;
    if (i < n0) {
        float4 a = *(const float4*)&wi[i], b = *(const float4*)&wi[i + 4];
        uint4 o = {pk2(a.x, a.y), pk2(a.z, a.w), pk2(b.x, b.y), pk2(b.z, b.w)};
        *(uint4*)&wi_bf[i] = o;
    }
    if (i < n1) {
        float4 a = *(const float4*)&wo[i], b = *(const float4*)&wo[i + 4];
        uint4 o = {pk2(a.x, a.y), pk2(a.z, a.w), pk2(b.x, b.y), pk2(b.z, b.w)};
        *(uint4*)&wo_bf[i] = o;
    }
    if (i < n2) {
        float4 a = *(const float4*)&wx[i], b = *(const float4*)&wx[i + 4];
        uint4 o = {pk2(a.x, a.y), pk2(a.z, a.w), pk2(b.x, b.y), pk2(b.z, b.w)};
        *(uint4*)&wx_bf[i] = o;
    }
    if (i < n3) {
        float4 a = *(const float4*)&A_log[i], b = *(const float4*)&A_log[i + 4];
        float4 ra = make_float4(-__expf(a.x), -__expf(a.y), -__expf(a.z), -__expf(a.w));
        float4 rb = make_float4(-__expf(b.x), -__expf(b.y), -__expf(b.z), -__expf(b.w));
        *(float4*)&negA[i] = ra;
        *(float4*)&negA[i + 4] = rb;
    }
    if (i < n4) {
        float4 a = *(const float4*)&x[i], b = *(const float4*)&x[i + 4];
        *(float4*)&xcur[i] = a;
        *(float4*)&xcur[i + 4] = b;
        float4 z = make_float4(0.f, 0.f, 0.f, 0.f);
        *(float4*)&res[i] = z;
        *(float4*)&res[i + 4] = z;
    }
    if (i < n5) {                       // dt_w -> bf16, K padded 48 -> 64
        int col = i & (KDT_ - 1);       // 8-aligned: group fully <48 or >=48
        int row = i >> 6;               // l*DI + n
        uint4 o = {0u, 0u, 0u, 0u};
        if (col < DR_) {
            const float* src = &wdt[(size_t)row * DR_ + col];
            float4 a = *(const float4*)src, b = *(const float4*)&src[4];
            o = (uint4){pk2(a.x, a.y), pk2(a.z, a.w), pk2(b.x, b.y), pk2(b.z, b.w)};
        }
        *(uint4*)&wdt_bf[i] = o;
    }
    if (i < n6) {                       // zero dbc_bf (pad cols stay 0 forever)
        *(uint4*)&dbc_bf[i] = (uint4){0u, 0u, 0u, 0u};
    }
}

// ---------------- block reduction helper (256 threads = 4 waves) ------------
__device__ __forceinline__ float block_sum256(float v) {
    __shared__ float sb[4];
    #pragma unroll
    for (int o = 32; o > 0; o >>= 1) v += __shfl_down(v, o);
    if ((threadIdx.x & 63) == 0) sb[threadIdx.x >> 6] = v;
    __syncthreads();
    float r = sb[0] + sb[1] + sb[2] + sb[3];
    __syncthreads();
    return r;
}

// ---------------- fused residual-accumulate + LayerNorm (bf16 out) ----------
__global__ __launch_bounds__(256) void ln_res_kernel(
    const float* __restrict__ xcur, float* __restrict__ res,
    const float* __restrict__ w, const float* __restrict__ b,
    unsigned short* __restrict__ xn) {
    int row = blockIdx.x;
    int t = threadIdx.x;
    size_t base = (size_t)row * D_;
    float v0 = xcur[base + t];
    float v1 = xcur[base + t + 256];
    float v2 = xcur[base + t + 512];
    res[base + t]       += v0;
    res[base + t + 256] += v1;
    res[base + t + 512] += v2;
    float mu = block_sum256(v0 + v1 + v2) * (1.0f / D_);
    float d0 = v0 - mu, d1 = v1 - mu, d2 = v2 - mu;
    float var = block_sum256(d0 * d0 + d1 * d1 + d2 * d2) * (1.0f / D_);
    float rs = rsqrtf(var + EPS_);
    xn[base + t]       = f2bf(d0 * rs * w[t]       + b[t]);
    xn[base + t + 256] = f2bf(d1 * rs * w[t + 256] + b[t + 256]);
    xn[base + t + 512] = f2bf(d2 * rs * w[t + 512] + b[t + 512]);
}

// ---------------- final LN: out = LN(xcur + res) ----------------------------
__global__ __launch_bounds__(256) void final_ln_kernel(
    const float* __restrict__ xcur, const float* __restrict__ res,
    const float* __restrict__ w, const float* __restrict__ b,
    float* __restrict__ out) {
    int row = blockIdx.x;
    int t = threadIdx.x;
    size_t base = (size_t)row * D_;
    float v0 = xcur[base + t]       + res[base + t];
    float v1 = xcur[base + t + 256] + res[base + t + 256];
    float v2 = xcur[base + t + 512] + res[base + t + 512];
    float mu = block_sum256(v0 + v1 + v2) * (1.0f / D_);
    float d0 = v0 - mu, d1 = v1 - mu, d2 = v2 - mu;
    float var = block_sum256(d0 * d0 + d1 * d1 + d2 * d2) * (1.0f / D_);
    float rs = rsqrtf(var + EPS_);
    out[base + t]       = d0 * rs * w[t]       + b[t];
    out[base + t + 256] = d1 * rs * w[t + 256] + b[t + 256];
    out[base + t + 512] = d2 * rs * w[t + 512] + b[t + 512];
}

// ---------------- bf16 MFMA GEMM: C[M,N] = A[M,K] * W[N,K]^T ---------------
// 2x2 wave layout; staging via async global_load_lds (width 16).
template <int BM, int BN>
__global__ __launch_bounds__(256) void gemm_bf16_t(
    const unsigned short* __restrict__ A,   // M x K bf16 row-major
    const unsigned short* __restrict__ W,   // N x K bf16 row-major
    float* __restrict__ C, int M, int N, int K) {
    constexpr int FM = BM / 32;             // 16x16 frags per wave (rows)
    constexpr int FN = BN / 32;             // 16x16 frags per wave (cols)
    constexpr int NLD = (BM + BN) / 64;     // 16B chunks per thread per k-tile
    __shared__ unsigned short sA[BM * 32];
    __shared__ unsigned short sW[BN * 32];
    int bm = blockIdx.y * BM, bn = blockIdx.x * BN;
    int tid = threadIdx.x;
    int wave = tid >> 6, lane = tid & 63;
    int wrow = (wave & 1) * (BM / 2), wcol = (wave >> 1) * (BN / 2);
    int quad = lane >> 4, r16 = lane & 15;
    f32x4 acc[FM][FN];
    #pragma unroll
    for (int i = 0; i < FM; i++)
        #pragma unroll
        for (int j = 0; j < FN; j++)
            acc[i][j] = (f32x4){0.f, 0.f, 0.f, 0.f};

    for (int k0 = 0; k0 < K; k0 += 32) {
        #pragma unroll
        for (int r = 0; r < NLD; r++) {
            if (r < BM / 64) {            // uniform per r (folds at unroll)
                int j = r * 256 + tid;    // chunk idx in sA; byte off = j*16
                gload16(&A[(size_t)(bm + (j >> 2)) * K + k0 + (j & 3) * 8],
                        &sA[(r * 256 + wave * 64) * 8]);
            } else {
                int j = (r - BM / 64) * 256 + tid;
                gload16(&W[(size_t)(bn + (j >> 2)) * K + k0 + (j & 3) * 8],
                        &sW[((r - BM / 64) * 256 + wave * 64) * 8]);
            }
        }
        __syncthreads();
        bf16x8 af[FM], wf[FN];
        #pragma unroll
        for (int i = 0; i < FM; i++)
            af[i] = *(const bf16x8*)&sA[(wrow + i * 16 + r16) * 32 + quad * 8];
        #pragma unroll
        for (int j = 0; j < FN; j++)
            wf[j] = *(const bf16x8*)&sW[(wcol + j * 16 + r16) * 32 + quad * 8];
        #pragma unroll
        for (int i = 0; i < FM; i++)
            #pragma unroll
            for (int j = 0; j < FN; j++)
                acc[i][j] = __builtin_amdgcn_mfma_f32_16x16x32_bf16(
                    af[i], wf[j], acc[i][j], 0, 0, 0);
        __syncthreads();
    }
    #pragma unroll
    for (int i = 0; i < FM; i++) {
        #pragma unroll
        for (int j = 0; j < FN; j++) {
            int col = bn + wcol + j * 16 + r16;
            #pragma unroll
            for (int reg = 0; reg < 4; reg++) {
                int row = bm + wrow + i * 16 + quad * 4 + reg;
                C[(size_t)row * N + col] = acc[i][j][reg];
            }
        }
    }
}

// ---------------- dt GEMM bf16 MFMA (M=2048, N=DI, K=64 padded) -------------
// epilogue: softplus(acc + bias) -> dtb (contiguous M x DI fp32)
__global__ __launch_bounds__(256) void dt_gemm_bf16(
    const unsigned short* __restrict__ A,   // M x 64 bf16 (dbc_bf, cols 48+ = 0)
    const unsigned short* __restrict__ W,   // DI x 64 bf16 (wdt_bf layer)
    const float* __restrict__ bias,         // DI
    float* __restrict__ dtb) {              // M x DI fp32
    __shared__ unsigned short sA[128 * 32];
    __shared__ unsigned short sW[128 * 32];
    int bm = blockIdx.y * 128, bn = blockIdx.x * 128;
    int tid = threadIdx.x;
    int wave = tid >> 6, lane = tid & 63;
    int wrow = (wave & 1) * 64, wcol = (wave >> 1) * 64;
    int quad = lane >> 4, r16 = lane & 15;
    f32x4 acc[4][4];
    #pragma unroll
    for (int i = 0; i < 4; i++)
        #pragma unroll
        for (int j = 0; j < 4; j++)
            acc[i][j] = (f32x4){0.f, 0.f, 0.f, 0.f};

    #pragma unroll
    for (int k0 = 0; k0 < KDT_; k0 += 32) {
        #pragma unroll
        for (int r = 0; r < 4; r++) {
            if (r < 2) {
                int j = r * 256 + tid;
                gload16(&A[(size_t)(bm + (j >> 2)) * KDT_ + k0 + (j & 3) * 8],
                        &sA[(r * 256 + wave * 64) * 8]);
            } else {
                int j = (r - 2) * 256 + tid;
                gload16(&W[(size_t)(bn + (j >> 2)) * KDT_ + k0 + (j & 3) * 8],
                        &sW[((r - 2) * 256 + wave * 64) * 8]);
            }
        }
        __syncthreads();
        bf16x8 af[4], wf[4];
        #pragma unroll
        for (int i = 0; i < 4; i++)
            af[i] = *(const bf16x8*)&sA[(wrow + i * 16 + r16) * 32 + quad * 8];
        #pragma unroll
        for (int j = 0; j < 4; j++)
            wf[j] = *(const bf16x8*)&sW[(wcol + j * 16 + r16) * 32 + quad * 8];
        #pragma unroll
        for (int i = 0; i < 4; i++)
            #pragma unroll
            for (int j = 0; j < 4; j++)
                acc[i][j] = __builtin_amdgcn_mfma_f32_16x16x32_bf16(
                    af[i], wf[j], acc[i][j], 0, 0, 0);
        __syncthreads();
    }
    #pragma unroll
    for (int i = 0; i < 4; i++) {
        #pragma unroll
        for (int j = 0; j < 4; j++) {
            int col = bn + wcol + j * 16 + r16;
            float bv = bias[col];
            #pragma unroll
            for (int reg = 0; reg < 4; reg++) {
                int row = bm + wrow + i * 16 + quad * 4 + reg;
                float v = acc[i][j][reg] + bv;
                v = (v > 20.f) ? v : log1pf(__expf(v));
                dtb[(size_t)row * DI_ + col] = v;
            }
        }
    }
}

// ---------------- x_proj GEMM: Pb[ks][M][80] partials, bf16 MFMA, split-K ---
__global__ __launch_bounds__(256) void xproj_gemm_kernel(
    const unsigned short* __restrict__ A,   // M x DI bf16 (xcb)
    const unsigned short* __restrict__ W,   // 80 x DI bf16
    float* __restrict__ Pb) {               // KS x M x 80 partials
    __shared__ unsigned short sA[64 * 32];
    __shared__ unsigned short sW[80 * 32];
    int ks = blockIdx.x;
    int bm = blockIdx.y * 64;
    int tid = threadIdx.x;
    int wave = tid >> 6, lane = tid & 63;
    int quad = lane >> 4, r16 = lane & 15;
    f32x4 acc[5];
    #pragma unroll
    for (int j = 0; j < 5; j++) acc[j] = (f32x4){0.f, 0.f, 0.f, 0.f};
    int k0base = ks * KCH_;
    for (int kc = 0; kc < KCH_; kc += 32) {
        int k0 = k0base + kc;
        gload16(&A[(size_t)(bm + (tid >> 2)) * DI_ + k0 + (tid & 3) * 8],
                &sA[wave * 512]);
        gload16(&W[(size_t)(tid >> 2) * DI_ + k0 + (tid & 3) * 8],
                &sW[wave * 512]);
        if (tid < 64) {
            int c = 256 + tid;
            gload16(&W[(size_t)(c >> 2) * DI_ + k0 + (c & 3) * 8],
                    &sW[2048]);
        }
        __syncthreads();
        bf16x8 af = *(const bf16x8*)&sA[(wave * 16 + r16) * 32 + quad * 8];
        #pragma unroll
        for (int j = 0; j < 5; j++) {
            bf16x8 wf = *(const bf16x8*)&sW[(j * 16 + r16) * 32 + quad * 8];
            acc[j] = __builtin_amdgcn_mfma_f32_16x16x32_bf16(af, wf, acc[j], 0, 0, 0);
        }
        __syncthreads();
    }
    #pragma unroll
    for (int j = 0; j < 5; j++) {
        int col = j * 16 + r16;
        #pragma unroll
        for (int reg = 0; reg < 4; reg++) {
            int row = bm + wave * 16 + quad * 4 + reg;
            Pb[((size_t)ks * M_ + row) * 80 + col] = acc[j][reg];
        }
    }
}

// reduce split-K partials; scatter into dbc_bf (M x 64 bf16) and packed BC
__global__ void xproj_reduce_kernel(const float* __restrict__ Pb,
                                    unsigned short* __restrict__ dbc_bf,
                                    float* __restrict__ bcp) {
    int i = blockIdx.x * 256 + threadIdx.x;   // over M_*80
    float s = 0.f;
    #pragma unroll
    for (int ks = 0; ks < KS_; ks++) s += Pb[(size_t)ks * (M_ * 80) + i];
    int m = i / 80, col = i % 80;
    if (col < DR_) {
        dbc_bf[m * KDT_ + col] = f2bf(s);
    } else if (col < DR_ + NS_) {
        bcp[m * 32 + 2 * (col - DR_)] = s;         // B_n
    } else {
        bcp[m * 32 + 2 * (col - DR_ - NS_) + 1] = s; // C_n
    }
}

// ---------------- causal depthwise conv (K=4) + bias + SiLU -----------------
__global__ void conv_silu_kernel(const float* __restrict__ xz,
                                 const float* __restrict__ cw,
                                 const float* __restrict__ cb,
                                 float* __restrict__ xcf,
                                 unsigned short* __restrict__ xcb) {
    int idx = blockIdx.x * blockDim.x + threadIdx.x;   // over B*L*DI
    if (idx >= B_ * L_ * DI_) return;
    int d = idx % DI_;
    int t = (idx / DI_) % L_;
    int b = idx / (DI_ * L_);
    float acc = cb[d];
    #pragma unroll
    for (int k = 0; k < KC_; k++) {
        int tt = t + k - (KC_ - 1);
        if (tt >= 0)
            acc += xz[((size_t)(b * L_ + tt)) * (2 * DI_) + d] * cw[d * KC_ + k];
    }
    float v = acc / (1.0f + __expf(-acc));
    xcf[idx] = v;
    xcb[idx] = f2bf(v);
}

// ---------------- scan pass 1: thread-per-channel, h[16] in registers -------
__global__ __launch_bounds__(256) void scan_chunk_kernel(
    const float* __restrict__ dtb,     // (B*L, DI) dt
    const float* __restrict__ xcf,     // (B*L, DI) xc
    const float4* __restrict__ bcp4,   // (B*L, 8) {B0,C0,B1,C1}x4 view
    const float* __restrict__ negA,    // (DI, NS) this layer
    float* __restrict__ Pbuf, float* __restrict__ Sbuf,
    float2* __restrict__ ylcd) {       // (B*L, DI) {y_local, cumdt}
    const int NDB = DI_ / 256;         // 6 d-blocks
    int bx = blockIdx.x;
    int dblk = bx % NDB;
    int c = (bx / NDB) % NC_;
    int b = bx / (NDB * NC_);
    int d = dblk * 256 + threadIdx.x;

    float A[NS_];
    #pragma unroll
    for (int n = 0; n < NS_; n++) A[n] = negA[(size_t)d * NS_ + n];
    float h[NS_];
    #pragma unroll
    for (int n = 0; n < NS_; n++) h[n] = 0.f;
    float sd = 0.f;

    size_t btbase = (size_t)(b * L_ + c * T_);
    const float* pdt = dtb + btbase * DI_ + d;
    const float* pxc = xcf + btbase * DI_ + d;
    const float4* pbc = bcp4 + btbase * 8;
    float2*       pyl = ylcd + btbase * DI_ + d;

    #pragma unroll
    for (int t = 0; t < T_; t++) {
        float dt = pdt[(size_t)t * DI_];
        float u  = dt * pxc[(size_t)t * DI_];
        sd += dt;
        float y = 0.f;
        #pragma unroll
        for (int q = 0; q < 8; q++) {
            float4 v = pbc[t * 8 + q];     // {B_2q, C_2q, B_2q+1, C_2q+1}
            float e0 = __expf(dt * A[2 * q]);
            h[2 * q] = fmaf(e0, h[2 * q], u * v.x);
            y = fmaf(v.y, h[2 * q], y);
            float e1 = __expf(dt * A[2 * q + 1]);
            h[2 * q + 1] = fmaf(e1, h[2 * q + 1], u * v.z);
            y = fmaf(v.w, h[2 * q + 1], y);
        }
        pyl[(size_t)t * DI_] = make_float2(y, sd);
    }

    size_t o = (((size_t)b * NC_ + c) * DI_ + d) * NS_;
    #pragma unroll
    for (int n = 0; n < NS_; n++) {
        Pbuf[o + n] = __expf(A[n] * sd);
        Sbuf[o + n] = h[n];
    }
}

// ---------------- scan pass 2: sequential combine over chunks ---------------
// 1-ahead register prefetch breaks the load->fma dependent chain.
__global__ __launch_bounds__(256) void scan_part2(
    const float* __restrict__ P, const float* __restrict__ S,
    float* __restrict__ hin) {
    int i = blockIdx.x * 256 + threadIdx.x;   // over B*DI*NS
    int b = i / (DI_ * NS_);
    int rem = i % (DI_ * NS_);
    const size_t str = (size_t)DI_ * NS_;
    size_t o = (size_t)b * NC_ * str + rem;
    float h = 0.f;
    float p = P[o], s = S[o];
    #pragma unroll 4
    for (int c = 0; c < NC_ - 1; c++) {
        float pn = P[o + str];
        float sn = S[o + str];
        hin[o] = h;
        h = fmaf(p, h, s);
        p = pn; s = sn;
        o += str;
    }
    hin[o] = h;
}

// ---------------- scan pass 3: PARALLEL finalize ----------------------------
__global__ __launch_bounds__(256) void scan_finalize_kernel(
    const float2* __restrict__ ylcd, const float* __restrict__ xcf,
    const float* __restrict__ bcp,    // (B*L, 32) interleaved {B,C}
    const float* __restrict__ xz, const float* __restrict__ negA,
    const float* __restrict__ Dp, const float* __restrict__ hin,
    unsigned short* __restrict__ yg) {
    int idx = blockIdx.x * 256 + threadIdx.x;   // over B*L*DI, d fastest
    int d = idx % DI_;
    int bt = idx / DI_;
    int b = bt / L_;
    int t = bt % L_;
    int c = t / T_;
    float2 yl = ylcd[idx];
    float cd = yl.y;
    const float4* hr4 = (const float4*)(hin + (((size_t)b * NC_ + c) * DI_ + d) * NS_);
    const float4* Ar4 = (const float4*)(negA + (size_t)d * NS_);
    const float4* bc4 = (const float4*)(bcp + (size_t)bt * 32);
    float corr = 0.f;
    #pragma unroll
    for (int q = 0; q < 4; q++) {
        float4 hv = hr4[q];
        float4 av = Ar4[q];
        float4 c0 = bc4[2 * q];       // {B,C,B,C}
        float4 c1 = bc4[2 * q + 1];
        corr += c0.y * __expf(av.x * cd) * hv.x;
        corr += c0.w * __expf(av.y * cd) * hv.y;
        corr += c1.y * __expf(av.z * cd) * hv.z;
        corr += c1.w * __expf(av.w * cd) * hv.w;
    }
    float xv = xcf[idx];
    float zv = xz[(size_t)bt * (2 * DI_) + DI_ + d];
    float yy = yl.x + corr + xv * Dp[d];
    yy *= zv / (1.0f + __expf(-zv));
    yg[idx] = f2bf(yy);
}

extern "C" void kernel_launch(void* const* d_in, const int* in_sizes, int n_in,
                              void* d_out, int out_size, void* d_ws, size_t ws_size,
                              hipStream_t stream) {
    const float* x        = (const float*)d_in[0];
    const float* ln_w     = (const float*)d_in[1];
    const float* ln_b     = (const float*)d_in[2];
    const float* in_proj  = (const float*)d_in[3];
    const float* conv_w   = (const float*)d_in[4];
    const float* conv_b   = (const float*)d_in[5];
    const float* x_proj   = (const float*)d_in[6];
    const float* dt_w     = (const float*)d_in[7];
    const float* dt_b     = (const float*)d_in[8];
    const float* A_log    = (const float*)d_in[9];
    const float* D_skip   = (const float*)d_in[10];
    const float* out_proj = (const float*)d_in[11];
    const float* fn_w     = (const float*)d_in[12];
    const float* fn_b     = (const float*)d_in[13];
    float* out = (float*)d_out;

    char* p = (char*)d_ws;
    auto alloc = [&](size_t bytes) {
        char* r = p;
        p += (bytes + 255) & ~(size_t)255;
        return (void*)r;
    };
    float* xcur = (float*)alloc((size_t)M_ * D_ * 4);
    float* res  = (float*)alloc((size_t)M_ * D_ * 4);
    unsigned short* xn = (unsigned short*)alloc((size_t)M_ * D_ * 2);
    float* xz   = (float*)alloc((size_t)M_ * 2 * DI_ * 4);
    unsigned short* xcb = (unsigned short*)alloc((size_t)M_ * DI_ * 2);
    float* dtb  = (float*)alloc((size_t)M_ * DI_ * 4);       // dt (contiguous)
    float* xcf  = (float*)alloc((size_t)M_ * DI_ * 4);       // conv+silu out
    unsigned short* dbc_bf = (unsigned short*)alloc((size_t)M_ * KDT_ * 2);
    float* bcp  = (float*)alloc((size_t)M_ * 32 * 4);        // {B,C} pairs x 16
    unsigned short* yg = (unsigned short*)alloc((size_t)M_ * DI_ * 2);
    float* Pbuf = (float*)alloc((size_t)B_ * NC_ * DI_ * NS_ * 4);   // 12.6 MB
    float* Sbuf = (float*)alloc((size_t)B_ * NC_ * DI_ * NS_ * 4);
    float* hin  = (float*)alloc((size_t)B_ * NC_ * DI_ * NS_ * 4);
    float* ylcd = (float*)alloc((size_t)M_ * DI_ * 2 * 4);   // {y_local, cumdt}
    float* Pb   = (float*)alloc((size_t)KS_ * M_ * 80 * 4);
    float* negA = (float*)alloc((size_t)NL_ * DI_ * NS_ * 4);
    const size_t n_wi = (size_t)NL_ * 2 * DI_ * D_;   // 18.87M
    const size_t n_wo = (size_t)NL_ * D_ * DI_;       // 9.44M
    const size_t n_wx = (size_t)NL_ * 80 * DI_;       // 0.98M
    const size_t n_wdt = (size_t)NL_ * DI_ * KDT_;    // 0.79M (padded)
    unsigned short* wi_bf = (unsigned short*)alloc(n_wi * 2);
    unsigned short* wo_bf = (unsigned short*)alloc(n_wo * 2);
    unsigned short* wx_bf = (unsigned short*)alloc(n_wx * 2);
    unsigned short* wdt_bf = (unsigned short*)alloc(n_wdt * 2);

    // fused prep: weight converts + negA + init (8 elems/thread, vectorized)
    prep_kernel<<<(int)((n_wi / 8 + 255) / 256), 256, 0, stream>>>(
        in_proj, wi_bf, (int)n_wi,
        out_proj, wo_bf, (int)n_wo,
        x_proj, wx_bf, (int)n_wx,
        A_log, negA, NL_ * DI_ * NS_,
        x, xcur, res, M_ * D_,
        dt_w, wdt_bf, (int)n_wdt,
        dbc_bf, M_ * KDT_);

    for (int l = 0; l < NL_; l++) {
        const float* negA_l = negA + (size_t)l * DI_ * NS_;

        ln_res_kernel<<<M_, 256, 0, stream>>>(
            xcur, res, ln_w + l * D_, ln_b + l * D_, xn);

        // xz = xn @ Wi^T   (M=2048, N=3072, K=768)  bf16 MFMA, 128x128 tiles
        gemm_bf16_t<128, 128><<<dim3((2 * DI_) / 128, M_ / 128), 256, 0, stream>>>(
            xn, wi_bf + (size_t)l * 2 * DI_ * D_, xz, M_, 2 * DI_, D_);

        conv_silu_kernel<<<(B_ * L_ * DI_ + 255) / 256, 256, 0, stream>>>(
            xz, conv_w + l * DI_ * KC_, conv_b + l * DI_, xcf, xcb);

        // dbc = xcb @ Wx^T  (M=2048, N=80, K=1536)  bf16 MFMA split-K
        xproj_gemm_kernel<<<dim3(KS_, M_ / 64), 256, 0, stream>>>(
            xcb, wx_bf + (size_t)l * 80 * DI_, Pb);
        xproj_reduce_kernel<<<(M_ * 80) / 256, 256, 0, stream>>>(Pb, dbc_bf, bcp);

        // dt = softplus(dbc_bf @ Wdt^T + bdt)  (M=2048, N=1536, K=64) bf16 MFMA
        dt_gemm_bf16<<<dim3(DI_ / 128, M_ / 128), 256, 0, stream>>>(
            dbc_bf, wdt_bf + (size_t)l * DI_ * KDT_, dt_b + l * DI_, dtb);

        // selective scan: thread-per-channel local scan + combine + finalize
        scan_chunk_kernel<<<B_ * NC_ * (DI_ / 256), 256, 0, stream>>>(
            dtb, xcf, (const float4*)bcp, negA_l,
            Pbuf, Sbuf, (float2*)ylcd);
        scan_part2<<<(B_ * DI_ * NS_) / 256, 256, 0, stream>>>(Pbuf, Sbuf, hin);
        scan_finalize_kernel<<<(M_ * DI_) / 256, 256, 0, stream>>>(
            (const float2*)ylcd, xcf, bcp, xz, negA_l,
            D_skip + (size_t)l * DI_, hin, yg);

        // xcur = yg @ Wo^T  (M=2048, N=768, K=1536)  bf16 MFMA, 128x64 tiles
        gemm_bf16_t<128, 64><<<dim3(D_ / 64, M_ / 128), 256, 0, stream>>>(
            yg, wo_bf + (size_t)l * D_ * DI_, xcur, M_, D_, DI_);
    }

    final_ln_kernel<<<M_, 256, 0, stream>>>(xcur, res, fn_w, fn_b, out);
}

// Round 3
// 1441.462 us; speedup vs baseline: 1.1956x; 1.1388x over previous
//
#include <hip/hip_runtime.h>
#include <math.h>

#define B_ 2
#define L_ 1024
#define D_ 768
#define NL_ 8
#define DI_ 1536
#define NS_ 16
#define DR_ 48
#define KC_ 4
#define EPS_ 1e-5f
#define M_ (B_*L_)   // 2048 rows
#define NC_ 64       // scan chunks (thread-per-channel layout)
#define T_ 16        // chunk length (NC_*T_ == L_)
#define KS_ 16       // x_proj split-K factor
#define KCH_ (DI_/KS_)   // 96 per split
#define KDT_ 64          // dt GEMM padded K (48 -> 64)

typedef short bf16x8 __attribute__((ext_vector_type(8)));
typedef float f32x4  __attribute__((ext_vector_type(4)));

// ---------------- fp32 -> bf16 (RNE) ---------------------------------------
__device__ __forceinline__ unsigned short f2bf(float f) {
    union { float f; unsigned int u; } v; v.f = f;
    unsigned int u = v.u;
    u += 0x7fffu + ((u >> 16) & 1u);
    return (unsigned short)(u >> 16);
}

__device__ __forceinline__ unsigned int pk2(float a, float b) {
    return (unsigned int)f2bf(a) | ((unsigned int)f2bf(b) << 16);
}

// async global->LDS, 16B per lane; LDS dest must be wave-uniform base + lane*16
__device__ __forceinline__ void gload16(const void* g, void* l) {
    __builtin_amdgcn_global_load_lds(
        (const __attribute__((address_space(1))) void*)g,
        (__attribute__((address_space(3))) void*)l, 16, 0, 0);
}

// convert 16 fp32 -> 16 bf16 (64B load, 32B store)
__device__ __forceinline__ void cvt16(const float* __restrict__ s,
                                      unsigned short* __restrict__ dst) {
    float4 a = *(const float4*)&s[0];
    float4 b = *(const float4*)&s[4];
    float4 c = *(const float4*)&s[8];
    float4 d = *(const float4*)&s[12];
    uint4 o0 = {pk2(a.x, a.y), pk2(a.z, a.w), pk2(b.x, b.y), pk2(b.z, b.w)};
    uint4 o1 = {pk2(c.x, c.y), pk2(c.z, c.w), pk2(d.x, d.y), pk2(d.z, d.w)};
    *(uint4*)&dst[0] = o0;
    *(uint4*)&dst[8] = o1;
}

// region-dispatched prep: each thread handles 16 elements of ONE stream.
// All region sizes are multiples of 16 (verified in launcher constants).
__global__ __launch_bounds__(256) void prep_kernel(
    const float* __restrict__ wi, unsigned short* __restrict__ wi_bf,
    const float* __restrict__ wo, unsigned short* __restrict__ wo_bf,
    const float* __restrict__ wx, unsigned short* __restrict__ wx_bf,
    const float* __restrict__ wdt, unsigned short* __restrict__ wdt_bf,
    const float* __restrict__ A_log, float* __restrict__ negA,
    const float* __restrict__ x, float* __restrict__ xcur,
    float* __restrict__ res,
    unsigned short* __restrict__ dbc_bf) {
    const int E0 = NL_ * 2 * DI_ * D_;   // 18874368 wi
    const int E1 = NL_ * D_ * DI_;       // 9437184  wo
    const int E2 = NL_ * 80 * DI_;       // 983040   wx
    const int E3 = NL_ * DI_ * KDT_;     // 786432   wdt (padded K)
    const int E4 = NL_ * DI_ * NS_;      // 196608   negA
    const int E5 = M_ * D_;              // 1572864  x / res init
    // E6 = M_*KDT_ = 131072 dbc zero
    int u = (blockIdx.x * 256 + threadIdx.x) * 16;
    if (u < E0) { cvt16(&wi[u], &wi_bf[u]); return; }
    u -= E0;
    if (u < E1) { cvt16(&wo[u], &wo_bf[u]); return; }
    u -= E1;
    if (u < E2) { cvt16(&wx[u], &wx_bf[u]); return; }
    u -= E2;
    if (u < E3) {                        // dt_w: K padded 48 -> 64, col grp of 16
        int col = u & (KDT_ - 1);
        if (col < DR_) {
            cvt16(&wdt[(size_t)(u >> 6) * DR_ + col], &wdt_bf[u]);
        } else {
            uint4 z = {0u, 0u, 0u, 0u};
            *(uint4*)&wdt_bf[u] = z;
            *(uint4*)&wdt_bf[u + 8] = z;
        }
        return;
    }
    u -= E3;
    if (u < E4) {                        // negA = -exp(A_log)
        #pragma unroll
        for (int r = 0; r < 4; r++) {
            float4 a = *(const float4*)&A_log[u + r * 4];
            float4 o = make_float4(-__expf(a.x), -__expf(a.y),
                                   -__expf(a.z), -__expf(a.w));
            *(float4*)&negA[u + r * 4] = o;
        }
        return;
    }
    u -= E4;
    if (u < E5) {                        // xcur = x; res = 0
        float4 z = make_float4(0.f, 0.f, 0.f, 0.f);
        #pragma unroll
        for (int r = 0; r < 4; r++) {
            *(float4*)&xcur[u + r * 4] = *(const float4*)&x[u + r * 4];
            *(float4*)&res[u + r * 4] = z;
        }
        return;
    }
    u -= E5;
    {                                    // zero dbc_bf pad (cols >= 48 stay 0)
        uint4 z = {0u, 0u, 0u, 0u};
        *(uint4*)&dbc_bf[u] = z;
        *(uint4*)&dbc_bf[u + 8] = z;
    }
}

// ---------------- block reduction helper (256 threads = 4 waves) ------------
__device__ __forceinline__ float block_sum256(float v) {
    __shared__ float sb[4];
    #pragma unroll
    for (int o = 32; o > 0; o >>= 1) v += __shfl_down(v, o);
    if ((threadIdx.x & 63) == 0) sb[threadIdx.x >> 6] = v;
    __syncthreads();
    float r = sb[0] + sb[1] + sb[2] + sb[3];
    __syncthreads();
    return r;
}

// ---------------- fused residual-accumulate + LayerNorm (bf16 out) ----------
__global__ __launch_bounds__(256) void ln_res_kernel(
    const float* __restrict__ xcur, float* __restrict__ res,
    const float* __restrict__ w, const float* __restrict__ b,
    unsigned short* __restrict__ xn) {
    int row = blockIdx.x;
    int t = threadIdx.x;
    size_t base = (size_t)row * D_;
    float v0 = xcur[base + t];
    float v1 = xcur[base + t + 256];
    float v2 = xcur[base + t + 512];
    res[base + t]       += v0;
    res[base + t + 256] += v1;
    res[base + t + 512] += v2;
    float mu = block_sum256(v0 + v1 + v2) * (1.0f / D_);
    float d0 = v0 - mu, d1 = v1 - mu, d2 = v2 - mu;
    float var = block_sum256(d0 * d0 + d1 * d1 + d2 * d2) * (1.0f / D_);
    float rs = rsqrtf(var + EPS_);
    xn[base + t]       = f2bf(d0 * rs * w[t]       + b[t]);
    xn[base + t + 256] = f2bf(d1 * rs * w[t + 256] + b[t + 256]);
    xn[base + t + 512] = f2bf(d2 * rs * w[t + 512] + b[t + 512]);
}

// ---------------- final LN: out = LN(xcur + res) ----------------------------
__global__ __launch_bounds__(256) void final_ln_kernel(
    const float* __restrict__ xcur, const float* __restrict__ res,
    const float* __restrict__ w, const float* __restrict__ b,
    float* __restrict__ out) {
    int row = blockIdx.x;
    int t = threadIdx.x;
    size_t base = (size_t)row * D_;
    float v0 = xcur[base + t]       + res[base + t];
    float v1 = xcur[base + t + 256] + res[base + t + 256];
    float v2 = xcur[base + t + 512] + res[base + t + 512];
    float mu = block_sum256(v0 + v1 + v2) * (1.0f / D_);
    float d0 = v0 - mu, d1 = v1 - mu, d2 = v2 - mu;
    float var = block_sum256(d0 * d0 + d1 * d1 + d2 * d2) * (1.0f / D_);
    float rs = rsqrtf(var + EPS_);
    out[base + t]       = d0 * rs * w[t]       + b[t];
    out[base + t + 256] = d1 * rs * w[t + 256] + b[t + 256];
    out[base + t + 512] = d2 * rs * w[t + 512] + b[t + 512];
}

// ---------------- bf16 MFMA GEMM: C[M,N] = A[M,K] * W[N,K]^T ---------------
// 2x2 wave layout; staging via async global_load_lds (width 16).
template <int BM, int BN>
__global__ __launch_bounds__(256) void gemm_bf16_t(
    const unsigned short* __restrict__ A,   // M x K bf16 row-major
    const unsigned short* __restrict__ W,   // N x K bf16 row-major
    float* __restrict__ C, int M, int N, int K) {
    constexpr int FM = BM / 32;             // 16x16 frags per wave (rows)
    constexpr int FN = BN / 32;             // 16x16 frags per wave (cols)
    constexpr int NLD = (BM + BN) / 64;     // 16B chunks per thread per k-tile
    __shared__ unsigned short sA[BM * 32];
    __shared__ unsigned short sW[BN * 32];
    int bm = blockIdx.y * BM, bn = blockIdx.x * BN;
    int tid = threadIdx.x;
    int wave = tid >> 6, lane = tid & 63;
    int wrow = (wave & 1) * (BM / 2), wcol = (wave >> 1) * (BN / 2);
    int quad = lane >> 4, r16 = lane & 15;
    f32x4 acc[FM][FN];
    #pragma unroll
    for (int i = 0; i < FM; i++)
        #pragma unroll
        for (int j = 0; j < FN; j++)
            acc[i][j] = (f32x4){0.f, 0.f, 0.f, 0.f};

    for (int k0 = 0; k0 < K; k0 += 32) {
        #pragma unroll
        for (int r = 0; r < NLD; r++) {
            if (r < BM / 64) {            // uniform per r (folds at unroll)
                int j = r * 256 + tid;    // chunk idx in sA; byte off = j*16
                gload16(&A[(size_t)(bm + (j >> 2)) * K + k0 + (j & 3) * 8],
                        &sA[(r * 256 + wave * 64) * 8]);
            } else {
                int j = (r - BM / 64) * 256 + tid;
                gload16(&W[(size_t)(bn + (j >> 2)) * K + k0 + (j & 3) * 8],
                        &sW[((r - BM / 64) * 256 + wave * 64) * 8]);
            }
        }
        __syncthreads();
        bf16x8 af[FM], wf[FN];
        #pragma unroll
        for (int i = 0; i < FM; i++)
            af[i] = *(const bf16x8*)&sA[(wrow + i * 16 + r16) * 32 + quad * 8];
        #pragma unroll
        for (int j = 0; j < FN; j++)
            wf[j] = *(const bf16x8*)&sW[(wcol + j * 16 + r16) * 32 + quad * 8];
        #pragma unroll
        for (int i = 0; i < FM; i++)
            #pragma unroll
            for (int j = 0; j < FN; j++)
                acc[i][j] = __builtin_amdgcn_mfma_f32_16x16x32_bf16(
                    af[i], wf[j], acc[i][j], 0, 0, 0);
        __syncthreads();
    }
    #pragma unroll
    for (int i = 0; i < FM; i++) {
        #pragma unroll
        for (int j = 0; j < FN; j++) {
            int col = bn + wcol + j * 16 + r16;
            #pragma unroll
            for (int reg = 0; reg < 4; reg++) {
                int row = bm + wrow + i * 16 + quad * 4 + reg;
                C[(size_t)row * N + col] = acc[i][j][reg];
            }
        }
    }
}

// ---------------- dt GEMM bf16 MFMA (M=2048, N=DI, K=64 padded) -------------
// epilogue: softplus(acc + bias) -> dtb (contiguous M x DI fp32)
__global__ __launch_bounds__(256) void dt_gemm_bf16(
    const unsigned short* __restrict__ A,   // M x 64 bf16 (dbc_bf, cols 48+ = 0)
    const unsigned short* __restrict__ W,   // DI x 64 bf16 (wdt_bf layer)
    const float* __restrict__ bias,         // DI
    float* __restrict__ dtb) {              // M x DI fp32
    __shared__ unsigned short sA[128 * 32];
    __shared__ unsigned short sW[128 * 32];
    int bm = blockIdx.y * 128, bn = blockIdx.x * 128;
    int tid = threadIdx.x;
    int wave = tid >> 6, lane = tid & 63;
    int wrow = (wave & 1) * 64, wcol = (wave >> 1) * 64;
    int quad = lane >> 4, r16 = lane & 15;
    f32x4 acc[4][4];
    #pragma unroll
    for (int i = 0; i < 4; i++)
        #pragma unroll
        for (int j = 0; j < 4; j++)
            acc[i][j] = (f32x4){0.f, 0.f, 0.f, 0.f};

    #pragma unroll
    for (int k0 = 0; k0 < KDT_; k0 += 32) {
        #pragma unroll
        for (int r = 0; r < 4; r++) {
            if (r < 2) {
                int j = r * 256 + tid;
                gload16(&A[(size_t)(bm + (j >> 2)) * KDT_ + k0 + (j & 3) * 8],
                        &sA[(r * 256 + wave * 64) * 8]);
            } else {
                int j = (r - 2) * 256 + tid;
                gload16(&W[(size_t)(bn + (j >> 2)) * KDT_ + k0 + (j & 3) * 8],
                        &sW[((r - 2) * 256 + wave * 64) * 8]);
            }
        }
        __syncthreads();
        bf16x8 af[4], wf[4];
        #pragma unroll
        for (int i = 0; i < 4; i++)
            af[i] = *(const bf16x8*)&sA[(wrow + i * 16 + r16) * 32 + quad * 8];
        #pragma unroll
        for (int j = 0; j < 4; j++)
            wf[j] = *(const bf16x8*)&sW[(wcol + j * 16 + r16) * 32 + quad * 8];
        #pragma unroll
        for (int i = 0; i < 4; i++)
            #pragma unroll
            for (int j = 0; j < 4; j++)
                acc[i][j] = __builtin_amdgcn_mfma_f32_16x16x32_bf16(
                    af[i], wf[j], acc[i][j], 0, 0, 0);
        __syncthreads();
    }
    #pragma unroll
    for (int i = 0; i < 4; i++) {
        #pragma unroll
        for (int j = 0; j < 4; j++) {
            int col = bn + wcol + j * 16 + r16;
            float bv = bias[col];
            #pragma unroll
            for (int reg = 0; reg < 4; reg++) {
                int row = bm + wrow + i * 16 + quad * 4 + reg;
                float v = acc[i][j][reg] + bv;
                v = (v > 20.f) ? v : log1pf(__expf(v));
                dtb[(size_t)row * DI_ + col] = v;
            }
        }
    }
}

// ---------------- x_proj GEMM: Pb[ks][M][80] partials, bf16 MFMA, split-K ---
__global__ __launch_bounds__(256) void xproj_gemm_kernel(
    const unsigned short* __restrict__ A,   // M x DI bf16 (xcb)
    const unsigned short* __restrict__ W,   // 80 x DI bf16
    float* __restrict__ Pb) {               // KS x M x 80 partials
    __shared__ unsigned short sA[64 * 32];
    __shared__ unsigned short sW[80 * 32];
    int ks = blockIdx.x;
    int bm = blockIdx.y * 64;
    int tid = threadIdx.x;
    int wave = tid >> 6, lane = tid & 63;
    int quad = lane >> 4, r16 = lane & 15;
    f32x4 acc[5];
    #pragma unroll
    for (int j = 0; j < 5; j++) acc[j] = (f32x4){0.f, 0.f, 0.f, 0.f};
    int k0base = ks * KCH_;
    for (int kc = 0; kc < KCH_; kc += 32) {
        int k0 = k0base + kc;
        gload16(&A[(size_t)(bm + (tid >> 2)) * DI_ + k0 + (tid & 3) * 8],
                &sA[wave * 512]);
        gload16(&W[(size_t)(tid >> 2) * DI_ + k0 + (tid & 3) * 8],
                &sW[wave * 512]);
        if (tid < 64) {
            int c = 256 + tid;
            gload16(&W[(size_t)(c >> 2) * DI_ + k0 + (c & 3) * 8],
                    &sW[2048]);
        }
        __syncthreads();
        bf16x8 af = *(const bf16x8*)&sA[(wave * 16 + r16) * 32 + quad * 8];
        #pragma unroll
        for (int j = 0; j < 5; j++) {
            bf16x8 wf = *(const bf16x8*)&sW[(j * 16 + r16) * 32 + quad * 8];
            acc[j] = __builtin_amdgcn_mfma_f32_16x16x32_bf16(af, wf, acc[j], 0, 0, 0);
        }
        __syncthreads();
    }
    #pragma unroll
    for (int j = 0; j < 5; j++) {
        int col = j * 16 + r16;
        #pragma unroll
        for (int reg = 0; reg < 4; reg++) {
            int row = bm + wave * 16 + quad * 4 + reg;
            Pb[((size_t)ks * M_ + row) * 80 + col] = acc[j][reg];
        }
    }
}

// reduce split-K partials; scatter into dbc_bf (M x 64 bf16) and packed BC
__global__ void xproj_reduce_kernel(const float* __restrict__ Pb,
                                    unsigned short* __restrict__ dbc_bf,
                                    float* __restrict__ bcp) {
    int i = blockIdx.x * 256 + threadIdx.x;   // over M_*80
    float s = 0.f;
    #pragma unroll
    for (int ks = 0; ks < KS_; ks++) s += Pb[(size_t)ks * (M_ * 80) + i];
    int m = i / 80, col = i % 80;
    if (col < DR_) {
        dbc_bf[m * KDT_ + col] = f2bf(s);
    } else if (col < DR_ + NS_) {
        bcp[m * 32 + 2 * (col - DR_)] = s;         // B_n
    } else {
        bcp[m * 32 + 2 * (col - DR_ - NS_) + 1] = s; // C_n
    }
}

// ---------------- causal depthwise conv (K=4) + bias + SiLU -----------------
// 4 timesteps per thread: 7 input loads for 4 outputs (was 16).
__global__ __launch_bounds__(256) void conv_silu_kernel(
    const float* __restrict__ xz,
    const float* __restrict__ cw,
    const float* __restrict__ cb,
    float* __restrict__ xcf,
    unsigned short* __restrict__ xcb) {
    int idx = blockIdx.x * 256 + threadIdx.x;   // over B*(L/4)*DI
    int d = idx % DI_;
    int t4 = (idx / DI_) % (L_ / 4);
    int b = idx / (DI_ * (L_ / 4));
    int t0 = t4 * 4;
    float4 wv = *(const float4*)&cw[d * KC_];
    float bias = cb[d];
    float xs[7];
    #pragma unroll
    for (int k = 0; k < 7; k++) {
        int tt = t0 - 3 + k;
        xs[k] = (tt >= 0) ? xz[((size_t)(b * L_ + tt)) * (2 * DI_) + d] : 0.f;
    }
    #pragma unroll
    for (int r = 0; r < 4; r++) {
        float acc = bias + xs[r] * wv.x + xs[r + 1] * wv.y
                         + xs[r + 2] * wv.z + xs[r + 3] * wv.w;
        float v = acc / (1.0f + __expf(-acc));
        size_t row = (size_t)(b * L_ + t0 + r);
        xcf[row * DI_ + d] = v;
        xcb[row * DI_ + d] = f2bf(v);
    }
}

// ---------------- scan pass A: per-chunk summaries only (P,S) --------------
__global__ __launch_bounds__(256) void scan_ps_kernel(
    const float* __restrict__ dtb,     // (B*L, DI) dt
    const float* __restrict__ xcf,     // (B*L, DI) xc
    const float4* __restrict__ bcp4,   // (B*L, 8) {B0,C0,B1,C1}x4 view
    const float* __restrict__ negA,    // (DI, NS) this layer
    float2* __restrict__ PS) {         // (B, NC, DI, NS) {P, S}
    const int NDB = DI_ / 256;         // 6 d-blocks
    int bx = blockIdx.x;
    int dblk = bx % NDB;
    int c = (bx / NDB) % NC_;
    int b = bx / (NDB * NC_);
    int d = dblk * 256 + threadIdx.x;

    float A[NS_];
    #pragma unroll
    for (int n = 0; n < NS_; n++) A[n] = negA[(size_t)d * NS_ + n];
    float h[NS_];
    #pragma unroll
    for (int n = 0; n < NS_; n++) h[n] = 0.f;
    float sd = 0.f;

    size_t btbase = (size_t)(b * L_ + c * T_);
    const float* pdt = dtb + btbase * DI_ + d;
    const float* pxc = xcf + btbase * DI_ + d;
    const float4* pbc = bcp4 + btbase * 8;

    #pragma unroll
    for (int t = 0; t < T_; t++) {
        float dt = pdt[(size_t)t * DI_];
        float u  = dt * pxc[(size_t)t * DI_];
        sd += dt;
        #pragma unroll
        for (int q = 0; q < 8; q++) {
            float4 v = pbc[t * 8 + q];     // {B_2q, C_2q, B_2q+1, C_2q+1}
            float e0 = __expf(dt * A[2 * q]);
            h[2 * q] = fmaf(e0, h[2 * q], u * v.x);
            float e1 = __expf(dt * A[2 * q + 1]);
            h[2 * q + 1] = fmaf(e1, h[2 * q + 1], u * v.z);
        }
    }

    size_t o = (((size_t)b * NC_ + c) * DI_ + d) * NS_;
    #pragma unroll
    for (int n = 0; n < NS_; n++)
        PS[o + n] = make_float2(__expf(A[n] * sd), h[n]);
}

// ---------------- scan pass B: sequential combine over chunks ---------------
__global__ __launch_bounds__(256) void scan_combine_kernel(
    const float2* __restrict__ PS, float* __restrict__ hin) {
    int i = blockIdx.x * 256 + threadIdx.x;   // over B*DI*NS
    int b = i / (DI_ * NS_);
    int rem = i % (DI_ * NS_);
    const size_t str = (size_t)DI_ * NS_;
    size_t o = (size_t)b * NC_ * str + rem;
    float h = 0.f;
    float2 ps = PS[o];
    #pragma unroll 4
    for (int c = 0; c < NC_ - 1; c++) {
        float2 psn = PS[o + str];
        hin[o] = h;
        h = fmaf(ps.x, h, ps.y);
        ps = psn;
        o += str;
    }
    hin[o] = h;
}

// ---------------- scan pass C: exact recurrence from hin -> yg --------------
__global__ __launch_bounds__(256) void scan_out_kernel(
    const float* __restrict__ dtb, const float* __restrict__ xcf,
    const float4* __restrict__ bcp4, const float* __restrict__ negA,
    const float* __restrict__ hin, const float* __restrict__ xz,
    const float* __restrict__ Dp, unsigned short* __restrict__ yg) {
    const int NDB = DI_ / 256;
    int bx = blockIdx.x;
    int dblk = bx % NDB;
    int c = (bx / NDB) % NC_;
    int b = bx / (NDB * NC_);
    int d = dblk * 256 + threadIdx.x;

    float A[NS_];
    #pragma unroll
    for (int n = 0; n < NS_; n++) A[n] = negA[(size_t)d * NS_ + n];
    size_t o = (((size_t)b * NC_ + c) * DI_ + d) * NS_;
    float h[NS_];
    #pragma unroll
    for (int n = 0; n < NS_; n++) h[n] = hin[o + n];
    float dpv = Dp[d];

    size_t btbase = (size_t)(b * L_ + c * T_);
    const float* pdt = dtb + btbase * DI_ + d;
    const float* pxc = xcf + btbase * DI_ + d;
    const float4* pbc = bcp4 + btbase * 8;

    #pragma unroll
    for (int t = 0; t < T_; t++) {
        float dt = pdt[(size_t)t * DI_];
        float xc = pxc[(size_t)t * DI_];
        float u = dt * xc;
        float y = 0.f;
        #pragma unroll
        for (int q = 0; q < 8; q++) {
            float4 v = pbc[t * 8 + q];     // {B_2q, C_2q, B_2q+1, C_2q+1}
            float e0 = __expf(dt * A[2 * q]);
            h[2 * q] = fmaf(e0, h[2 * q], u * v.x);
            y = fmaf(v.y, h[2 * q], y);
            float e1 = __expf(dt * A[2 * q + 1]);
            h[2 * q + 1] = fmaf(e1, h[2 * q + 1], u * v.z);
            y = fmaf(v.w, h[2 * q + 1], y);
        }
        size_t row = btbase + t;
        float zv = xz[row * (2 * DI_) + DI_ + d];
        float yy = y + xc * dpv;
        yy *= zv / (1.0f + __expf(-zv));
        yg[row * DI_ + d] = f2bf(yy);
    }
}

extern "C" void kernel_launch(void* const* d_in, const int* in_sizes, int n_in,
                              void* d_out, int out_size, void* d_ws, size_t ws_size,
                              hipStream_t stream) {
    const float* x        = (const float*)d_in[0];
    const float* ln_w     = (const float*)d_in[1];
    const float* ln_b     = (const float*)d_in[2];
    const float* in_proj  = (const float*)d_in[3];
    const float* conv_w   = (const float*)d_in[4];
    const float* conv_b   = (const float*)d_in[5];
    const float* x_proj   = (const float*)d_in[6];
    const float* dt_w     = (const float*)d_in[7];
    const float* dt_b     = (const float*)d_in[8];
    const float* A_log    = (const float*)d_in[9];
    const float* D_skip   = (const float*)d_in[10];
    const float* out_proj = (const float*)d_in[11];
    const float* fn_w     = (const float*)d_in[12];
    const float* fn_b     = (const float*)d_in[13];
    float* out = (float*)d_out;

    char* p = (char*)d_ws;
    auto alloc = [&](size_t bytes) {
        char* r = p;
        p += (bytes + 255) & ~(size_t)255;
        return (void*)r;
    };
    float* xcur = (float*)alloc((size_t)M_ * D_ * 4);
    float* res  = (float*)alloc((size_t)M_ * D_ * 4);
    unsigned short* xn = (unsigned short*)alloc((size_t)M_ * D_ * 2);
    float* xz   = (float*)alloc((size_t)M_ * 2 * DI_ * 4);
    unsigned short* xcb = (unsigned short*)alloc((size_t)M_ * DI_ * 2);
    float* dtb  = (float*)alloc((size_t)M_ * DI_ * 4);       // dt (contiguous)
    float* xcf  = (float*)alloc((size_t)M_ * DI_ * 4);       // conv+silu out
    unsigned short* dbc_bf = (unsigned short*)alloc((size_t)M_ * KDT_ * 2);
    float* bcp  = (float*)alloc((size_t)M_ * 32 * 4);        // {B,C} pairs x 16
    unsigned short* yg = (unsigned short*)alloc((size_t)M_ * DI_ * 2);
    float2* PS  = (float2*)alloc((size_t)B_ * NC_ * DI_ * NS_ * 8);  // 25.2 MB
    float* hin  = (float*)alloc((size_t)B_ * NC_ * DI_ * NS_ * 4);
    float* Pb   = (float*)alloc((size_t)KS_ * M_ * 80 * 4);
    float* negA = (float*)alloc((size_t)NL_ * DI_ * NS_ * 4);
    const size_t n_wi = (size_t)NL_ * 2 * DI_ * D_;   // 18.87M
    const size_t n_wo = (size_t)NL_ * D_ * DI_;       // 9.44M
    const size_t n_wx = (size_t)NL_ * 80 * DI_;       // 0.98M
    const size_t n_wdt = (size_t)NL_ * DI_ * KDT_;    // 0.79M (padded)
    unsigned short* wi_bf = (unsigned short*)alloc(n_wi * 2);
    unsigned short* wo_bf = (unsigned short*)alloc(n_wo * 2);
    unsigned short* wx_bf = (unsigned short*)alloc(n_wx * 2);
    unsigned short* wdt_bf = (unsigned short*)alloc(n_wdt * 2);

    // region-dispatched prep: 16 elems/thread, one stream per thread.
    // total elems = wi + wo + wx + wdt + negA + init + dbczero
    //             = 31981568; /16/256 = 7808 blocks exactly.
    prep_kernel<<<7808, 256, 0, stream>>>(
        in_proj, wi_bf, out_proj, wo_bf, x_proj, wx_bf,
        dt_w, wdt_bf, A_log, negA, x, xcur, res, dbc_bf);

    for (int l = 0; l < NL_; l++) {
        const float* negA_l = negA + (size_t)l * DI_ * NS_;

        ln_res_kernel<<<M_, 256, 0, stream>>>(
            xcur, res, ln_w + l * D_, ln_b + l * D_, xn);

        // xz = xn @ Wi^T   (M=2048, N=3072, K=768)  bf16 MFMA, 128x128 tiles
        gemm_bf16_t<128, 128><<<dim3((2 * DI_) / 128, M_ / 128), 256, 0, stream>>>(
            xn, wi_bf + (size_t)l * 2 * DI_ * D_, xz, M_, 2 * DI_, D_);

        conv_silu_kernel<<<(B_ * (L_ / 4) * DI_) / 256, 256, 0, stream>>>(
            xz, conv_w + l * DI_ * KC_, conv_b + l * DI_, xcf, xcb);

        // dbc = xcb @ Wx^T  (M=2048, N=80, K=1536)  bf16 MFMA split-K
        xproj_gemm_kernel<<<dim3(KS_, M_ / 64), 256, 0, stream>>>(
            xcb, wx_bf + (size_t)l * 80 * DI_, Pb);
        xproj_reduce_kernel<<<(M_ * 80) / 256, 256, 0, stream>>>(Pb, dbc_bf, bcp);

        // dt = softplus(dbc_bf @ Wdt^T + bdt)  (M=2048, N=1536, K=64) bf16 MFMA
        dt_gemm_bf16<<<dim3(DI_ / 128, M_ / 128), 256, 0, stream>>>(
            dbc_bf, wdt_bf + (size_t)l * DI_ * KDT_, dt_b + l * DI_, dtb);

        // selective scan: summaries -> combine -> exact recurrence + output
        scan_ps_kernel<<<B_ * NC_ * (DI_ / 256), 256, 0, stream>>>(
            dtb, xcf, (const float4*)bcp, negA_l, PS);
        scan_combine_kernel<<<(B_ * DI_ * NS_) / 256, 256, 0, stream>>>(PS, hin);
        scan_out_kernel<<<B_ * NC_ * (DI_ / 256), 256, 0, stream>>>(
            dtb, xcf, (const float4*)bcp, negA_l, hin, xz,
            D_skip + (size_t)l * DI_, yg);

        // xcur = yg @ Wo^T  (M=2048, N=768, K=1536)  bf16 MFMA, 128x64 tiles
        gemm_bf16_t<128, 64><<<dim3(D_ / 64, M_ / 128), 256, 0, stream>>>(
            yg, wo_bf + (size_t)l * D_ * DI_, xcur, M_, D_, DI_);
    }

    final_ln_kernel<<<M_, 256, 0, stream>>>(xcur, res, fn_w, fn_b, out);
}

// Round 4
// 1407.569 us; speedup vs baseline: 1.2244x; 1.0241x over previous
//
#include <hip/hip_runtime.h>
#include <math.h>

#define B_ 2
#define L_ 1024
#define D_ 768
#define NL_ 8
#define DI_ 1536
#define NS_ 16
#define DR_ 48
#define KC_ 4
#define EPS_ 1e-5f
#define M_ (B_*L_)   // 2048 rows
#define NC_ 64       // scan chunks (thread-per-channel layout)
#define T_ 16        // chunk length (NC_*T_ == L_)
#define KS_ 16       // x_proj split-K factor
#define KCH_ (DI_/KS_)   // 96 per split
#define KDT_ 64          // dt GEMM padded K (48 -> 64)

typedef short bf16x8 __attribute__((ext_vector_type(8)));
typedef float f32x4  __attribute__((ext_vector_type(4)));

// ---------------- fp32 -> bf16 (RNE) ---------------------------------------
__device__ __forceinline__ unsigned short f2bf(float f) {
    union { float f; unsigned int u; } v; v.f = f;
    unsigned int u = v.u;
    u += 0x7fffu + ((u >> 16) & 1u);
    return (unsigned short)(u >> 16);
}

__device__ __forceinline__ unsigned int pk2(float a, float b) {
    union { float f; unsigned int u; } va, vb;
    va.f = a; vb.f = b;
    unsigned int ua = va.u + (0x7fffu + ((va.u >> 16) & 1u));
    unsigned int ub = vb.u + (0x7fffu + ((vb.u >> 16) & 1u));
    return (ua >> 16) | (ub & 0xffff0000u);
}

// async global->LDS, 16B per lane; LDS dest must be wave-uniform base + lane*16
__device__ __forceinline__ void gload16(const void* g, void* l) {
    __builtin_amdgcn_global_load_lds(
        (const __attribute__((address_space(1))) void*)g,
        (__attribute__((address_space(3))) void*)l, 16, 0, 0);
}

// ---------------- prep: region-dispatched, block owns 4096 contiguous elems -
// thread accesses tid*4 + r*1024 -> lane-contiguous 16B loads (coalesced).
// All region sizes are multiples of 4096 (asserted by launcher constants).
__device__ __forceinline__ void cvt_blk(const float* __restrict__ s,
                                        unsigned short* __restrict__ d, int tid) {
    #pragma unroll
    for (int r = 0; r < 4; r++) {
        int off = tid * 4 + r * 1024;
        float4 a = *(const float4*)&s[off];
        uint2 o = {pk2(a.x, a.y), pk2(a.z, a.w)};
        *(uint2*)&d[off] = o;
    }
}

__global__ __launch_bounds__(256) void prep_kernel(
    const float* __restrict__ wi, unsigned short* __restrict__ wi_bf,
    const float* __restrict__ wo, unsigned short* __restrict__ wo_bf,
    const float* __restrict__ wx, unsigned short* __restrict__ wx_bf,
    const float* __restrict__ wdt, unsigned short* __restrict__ wdt_bf,
    const float* __restrict__ A_log, float* __restrict__ negA,
    const float* __restrict__ x, float* __restrict__ xcur,
    float* __restrict__ res,
    unsigned short* __restrict__ dbc_bf) {
    const int E0 = NL_ * 2 * DI_ * D_;   // 18874368 wi   (/4096 = 4608)
    const int E1 = NL_ * D_ * DI_;       // 9437184  wo   (2304)
    const int E2 = NL_ * 80 * DI_;       // 983040   wx   (240)
    const int E3 = NL_ * DI_ * KDT_;     // 786432   wdt  (192)
    const int E4 = NL_ * DI_ * NS_;      // 196608   negA (48)
    const int E5 = M_ * D_;              // 1572864  init (384)
    int tid = threadIdx.x;
    int base = blockIdx.x * 4096;
    if (base < E0) { cvt_blk(wi + base, wi_bf + base, tid); return; }
    base -= E0;
    if (base < E1) { cvt_blk(wo + base, wo_bf + base, tid); return; }
    base -= E1;
    if (base < E2) { cvt_blk(wx + base, wx_bf + base, tid); return; }
    base -= E2;
    if (base < E3) {                     // dt_w: K padded 48 -> 64
        #pragma unroll
        for (int r = 0; r < 4; r++) {
            int off = base + tid * 4 + r * 1024;
            int col = off & (KDT_ - 1);
            uint2 o = {0u, 0u};
            if (col < DR_) {
                float4 a = *(const float4*)&wdt[(size_t)(off >> 6) * DR_ + col];
                o = (uint2){pk2(a.x, a.y), pk2(a.z, a.w)};
            }
            *(uint2*)&wdt_bf[off] = o;
        }
        return;
    }
    base -= E3;
    if (base < E4) {                     // negA = -exp(A_log)
        #pragma unroll
        for (int r = 0; r < 4; r++) {
            int off = base + tid * 4 + r * 1024;
            float4 a = *(const float4*)&A_log[off];
            float4 o = make_float4(-__expf(a.x), -__expf(a.y),
                                   -__expf(a.z), -__expf(a.w));
            *(float4*)&negA[off] = o;
        }
        return;
    }
    base -= E4;
    if (base < E5) {                     // xcur = x; res = 0
        float4 z = make_float4(0.f, 0.f, 0.f, 0.f);
        #pragma unroll
        for (int r = 0; r < 4; r++) {
            int off = base + tid * 4 + r * 1024;
            *(float4*)&xcur[off] = *(const float4*)&x[off];
            *(float4*)&res[off] = z;
        }
        return;
    }
    base -= E5;
    {                                    // zero dbc_bf pad (cols >= 48 stay 0)
        #pragma unroll
        for (int r = 0; r < 4; r++) {
            int off = base + tid * 4 + r * 1024;
            *(uint2*)&dbc_bf[off] = (uint2){0u, 0u};
        }
    }
}

// ---------------- block reduction helper (256 threads = 4 waves) ------------
__device__ __forceinline__ float block_sum256(float v) {
    __shared__ float sb[4];
    #pragma unroll
    for (int o = 32; o > 0; o >>= 1) v += __shfl_down(v, o);
    if ((threadIdx.x & 63) == 0) sb[threadIdx.x >> 6] = v;
    __syncthreads();
    float r = sb[0] + sb[1] + sb[2] + sb[3];
    __syncthreads();
    return r;
}

// ---------------- fused residual-accumulate + LayerNorm (bf16 out) ----------
__global__ __launch_bounds__(256) void ln_res_kernel(
    const float* __restrict__ xcur, float* __restrict__ res,
    const float* __restrict__ w, const float* __restrict__ b,
    unsigned short* __restrict__ xn) {
    int row = blockIdx.x;
    int t = threadIdx.x;
    size_t base = (size_t)row * D_;
    float v0 = xcur[base + t];
    float v1 = xcur[base + t + 256];
    float v2 = xcur[base + t + 512];
    res[base + t]       += v0;
    res[base + t + 256] += v1;
    res[base + t + 512] += v2;
    float mu = block_sum256(v0 + v1 + v2) * (1.0f / D_);
    float d0 = v0 - mu, d1 = v1 - mu, d2 = v2 - mu;
    float var = block_sum256(d0 * d0 + d1 * d1 + d2 * d2) * (1.0f / D_);
    float rs = rsqrtf(var + EPS_);
    xn[base + t]       = f2bf(d0 * rs * w[t]       + b[t]);
    xn[base + t + 256] = f2bf(d1 * rs * w[t + 256] + b[t + 256]);
    xn[base + t + 512] = f2bf(d2 * rs * w[t + 512] + b[t + 512]);
}

// ---------------- final LN: out = LN(xcur + res) ----------------------------
__global__ __launch_bounds__(256) void final_ln_kernel(
    const float* __restrict__ xcur, const float* __restrict__ res,
    const float* __restrict__ w, const float* __restrict__ b,
    float* __restrict__ out) {
    int row = blockIdx.x;
    int t = threadIdx.x;
    size_t base = (size_t)row * D_;
    float v0 = xcur[base + t]       + res[base + t];
    float v1 = xcur[base + t + 256] + res[base + t + 256];
    float v2 = xcur[base + t + 512] + res[base + t + 512];
    float mu = block_sum256(v0 + v1 + v2) * (1.0f / D_);
    float d0 = v0 - mu, d1 = v1 - mu, d2 = v2 - mu;
    float var = block_sum256(d0 * d0 + d1 * d1 + d2 * d2) * (1.0f / D_);
    float rs = rsqrtf(var + EPS_);
    out[base + t]       = d0 * rs * w[t]       + b[t];
    out[base + t + 256] = d1 * rs * w[t + 256] + b[t + 256];
    out[base + t + 512] = d2 * rs * w[t + 512] + b[t + 512];
}

// ---------------- bf16 MFMA GEMM: C[M,N] = A[M,K] * W[N,K]^T ---------------
// 2x2 wave layout; staging via async global_load_lds (width 16).
template <int BM, int BN>
__global__ __launch_bounds__(256) void gemm_bf16_t(
    const unsigned short* __restrict__ A,   // M x K bf16 row-major
    const unsigned short* __restrict__ W,   // N x K bf16 row-major
    float* __restrict__ C, int M, int N, int K) {
    constexpr int FM = BM / 32;             // 16x16 frags per wave (rows)
    constexpr int FN = BN / 32;             // 16x16 frags per wave (cols)
    constexpr int NLD = (BM + BN) / 64;     // 16B chunks per thread per k-tile
    __shared__ unsigned short sA[BM * 32];
    __shared__ unsigned short sW[BN * 32];
    int bm = blockIdx.y * BM, bn = blockIdx.x * BN;
    int tid = threadIdx.x;
    int wave = tid >> 6, lane = tid & 63;
    int wrow = (wave & 1) * (BM / 2), wcol = (wave >> 1) * (BN / 2);
    int quad = lane >> 4, r16 = lane & 15;
    f32x4 acc[FM][FN];
    #pragma unroll
    for (int i = 0; i < FM; i++)
        #pragma unroll
        for (int j = 0; j < FN; j++)
            acc[i][j] = (f32x4){0.f, 0.f, 0.f, 0.f};

    for (int k0 = 0; k0 < K; k0 += 32) {
        #pragma unroll
        for (int r = 0; r < NLD; r++) {
            if (r < BM / 64) {            // uniform per r (folds at unroll)
                int j = r * 256 + tid;    // chunk idx in sA; byte off = j*16
                gload16(&A[(size_t)(bm + (j >> 2)) * K + k0 + (j & 3) * 8],
                        &sA[(r * 256 + wave * 64) * 8]);
            } else {
                int j = (r - BM / 64) * 256 + tid;
                gload16(&W[(size_t)(bn + (j >> 2)) * K + k0 + (j & 3) * 8],
                        &sW[((r - BM / 64) * 256 + wave * 64) * 8]);
            }
        }
        __syncthreads();
        bf16x8 af[FM], wf[FN];
        #pragma unroll
        for (int i = 0; i < FM; i++)
            af[i] = *(const bf16x8*)&sA[(wrow + i * 16 + r16) * 32 + quad * 8];
        #pragma unroll
        for (int j = 0; j < FN; j++)
            wf[j] = *(const bf16x8*)&sW[(wcol + j * 16 + r16) * 32 + quad * 8];
        #pragma unroll
        for (int i = 0; i < FM; i++)
            #pragma unroll
            for (int j = 0; j < FN; j++)
                acc[i][j] = __builtin_amdgcn_mfma_f32_16x16x32_bf16(
                    af[i], wf[j], acc[i][j], 0, 0, 0);
        __syncthreads();
    }
    #pragma unroll
    for (int i = 0; i < FM; i++) {
        #pragma unroll
        for (int j = 0; j < FN; j++) {
            int col = bn + wcol + j * 16 + r16;
            #pragma unroll
            for (int reg = 0; reg < 4; reg++) {
                int row = bm + wrow + i * 16 + quad * 4 + reg;
                C[(size_t)row * N + col] = acc[i][j][reg];
            }
        }
    }
}

// ---------------- dt GEMM bf16 MFMA (M=2048, N=DI, K=64 padded) -------------
// epilogue: softplus(acc + bias) -> dtb (contiguous M x DI fp32)
__global__ __launch_bounds__(256) void dt_gemm_bf16(
    const unsigned short* __restrict__ A,   // M x 64 bf16 (dbc_bf, cols 48+ = 0)
    const unsigned short* __restrict__ W,   // DI x 64 bf16 (wdt_bf layer)
    const float* __restrict__ bias,         // DI
    float* __restrict__ dtb) {              // M x DI fp32
    __shared__ unsigned short sA[128 * 32];
    __shared__ unsigned short sW[128 * 32];
    int bm = blockIdx.y * 128, bn = blockIdx.x * 128;
    int tid = threadIdx.x;
    int wave = tid >> 6, lane = tid & 63;
    int wrow = (wave & 1) * 64, wcol = (wave >> 1) * 64;
    int quad = lane >> 4, r16 = lane & 15;
    f32x4 acc[4][4];
    #pragma unroll
    for (int i = 0; i < 4; i++)
        #pragma unroll
        for (int j = 0; j < 4; j++)
            acc[i][j] = (f32x4){0.f, 0.f, 0.f, 0.f};

    #pragma unroll
    for (int k0 = 0; k0 < KDT_; k0 += 32) {
        #pragma unroll
        for (int r = 0; r < 4; r++) {
            if (r < 2) {
                int j = r * 256 + tid;
                gload16(&A[(size_t)(bm + (j >> 2)) * KDT_ + k0 + (j & 3) * 8],
                        &sA[(r * 256 + wave * 64) * 8]);
            } else {
                int j = (r - 2) * 256 + tid;
                gload16(&W[(size_t)(bn + (j >> 2)) * KDT_ + k0 + (j & 3) * 8],
                        &sW[((r - 2) * 256 + wave * 64) * 8]);
            }
        }
        __syncthreads();
        bf16x8 af[4], wf[4];
        #pragma unroll
        for (int i = 0; i < 4; i++)
            af[i] = *(const bf16x8*)&sA[(wrow + i * 16 + r16) * 32 + quad * 8];
        #pragma unroll
        for (int j = 0; j < 4; j++)
            wf[j] = *(const bf16x8*)&sW[(wcol + j * 16 + r16) * 32 + quad * 8];
        #pragma unroll
        for (int i = 0; i < 4; i++)
            #pragma unroll
            for (int j = 0; j < 4; j++)
                acc[i][j] = __builtin_amdgcn_mfma_f32_16x16x32_bf16(
                    af[i], wf[j], acc[i][j], 0, 0, 0);
        __syncthreads();
    }
    #pragma unroll
    for (int i = 0; i < 4; i++) {
        #pragma unroll
        for (int j = 0; j < 4; j++) {
            int col = bn + wcol + j * 16 + r16;
            float bv = bias[col];
            #pragma unroll
            for (int reg = 0; reg < 4; reg++) {
                int row = bm + wrow + i * 16 + quad * 4 + reg;
                float v = acc[i][j][reg] + bv;
                v = (v > 20.f) ? v : log1pf(__expf(v));
                dtb[(size_t)row * DI_ + col] = v;
            }
        }
    }
}

// ---------------- fused conv+SiLU+x_proj GEMM (split-K over ks) -------------
// block (ks, bm): conv for rows [bm,bm+64) cols [ks*96,(ks+1)*96) computed in
// LDS from an xz tile with 3 halo rows; writes xcf once; bf16 tile stays in
// LDS (padded stride 104: 2-way-free banks for b128 frag reads) -> MFMA.
__global__ __launch_bounds__(256) void conv_xproj_kernel(
    const float* __restrict__ xz,           // M x 2DI fp32 (xi half used)
    const float* __restrict__ cw,           // DI x 4
    const float* __restrict__ cb,           // DI
    const unsigned short* __restrict__ W,   // 80 x DI bf16 (wx_bf layer)
    float* __restrict__ xcf,                // M x DI fp32 (conv+silu out)
    float* __restrict__ Pb) {               // KS x M x 80 partials
    __shared__ float sxz[67 * 96];              // 25.1 KB (aliased by sW below)
    __shared__ unsigned short sxcb[64 * 104];   // 13.3 KB (padded)
    __shared__ float scw[96 * 4];
    __shared__ float scb[96];
    unsigned short* sW = (unsigned short*)sxz;  // [80][104] = 16.6 KB, fits

    int ks = blockIdx.x;
    int bm = blockIdx.y * 64;
    int tid = threadIdx.x;
    int b = bm >> 10, t0 = bm & (L_ - 1);
    int dbase = ks * KCH_;

    if (tid < 96) {
        int d = dbase + tid;
        *(float4*)&scw[tid * 4] = *(const float4*)&cw[d * 4];
        scb[tid] = cb[d];
    }
    // stage xz xi-tile rows t0-3 .. t0+63 (zeros for t<0)
    for (int j = tid; j < 67 * 24; j += 256) {
        int r = j / 24, c4 = (j % 24) * 4;
        int tt = t0 + r - 3;
        float4 v = make_float4(0.f, 0.f, 0.f, 0.f);
        if (tt >= 0)
            v = *(const float4*)&xz[((size_t)(b * L_ + tt)) * (2 * DI_) + dbase + c4];
        *(float4*)&sxz[r * 96 + c4] = v;
    }
    __syncthreads();
    // conv + bias + SiLU: 64 x 96 outputs
    for (int j = tid; j < 64 * 96; j += 256) {
        int r = j / 96, c = j % 96;
        float acc = scb[c];
        #pragma unroll
        for (int k = 0; k < KC_; k++)
            acc = fmaf(scw[c * 4 + k], sxz[(r + k) * 96 + c], acc);
        float v = acc / (1.0f + __expf(-acc));
        xcf[(size_t)(bm + r) * DI_ + dbase + c] = v;
        sxcb[r * 104 + c] = f2bf(v);
    }
    __syncthreads();                 // all sxz reads done; safe to alias
    // stage Wx slice (80 x 96) into padded sW
    for (int j = tid; j < 80 * 12; j += 256) {
        int row = j / 12, c16 = (j % 12) * 8;
        *(uint4*)&sW[row * 104 + c16] =
            *(const uint4*)&W[(size_t)row * DI_ + dbase + c16];
    }
    __syncthreads();
    // GEMM: 4 waves x 16-row groups, K = 96 (3 steps of 32)
    int wave = tid >> 6, lane = tid & 63;
    int quad = lane >> 4, r16 = lane & 15;
    f32x4 acc[5];
    #pragma unroll
    for (int j = 0; j < 5; j++) acc[j] = (f32x4){0.f, 0.f, 0.f, 0.f};
    #pragma unroll
    for (int kk = 0; kk < 3; kk++) {
        bf16x8 af = *(const bf16x8*)&sxcb[(wave * 16 + r16) * 104 + kk * 32 + quad * 8];
        #pragma unroll
        for (int j = 0; j < 5; j++) {
            bf16x8 wf = *(const bf16x8*)&sW[(j * 16 + r16) * 104 + kk * 32 + quad * 8];
            acc[j] = __builtin_amdgcn_mfma_f32_16x16x32_bf16(af, wf, acc[j], 0, 0, 0);
        }
    }
    #pragma unroll
    for (int j = 0; j < 5; j++) {
        int col = j * 16 + r16;
        #pragma unroll
        for (int reg = 0; reg < 4; reg++) {
            int row = bm + wave * 16 + quad * 4 + reg;
            Pb[((size_t)ks * M_ + row) * 80 + col] = acc[j][reg];
        }
    }
}

// reduce split-K partials; scatter into dbc_bf (M x 64 bf16) and packed BC
__global__ void xproj_reduce_kernel(const float* __restrict__ Pb,
                                    unsigned short* __restrict__ dbc_bf,
                                    float* __restrict__ bcp) {
    int i = blockIdx.x * 256 + threadIdx.x;   // over M_*80
    float s = 0.f;
    #pragma unroll
    for (int ks = 0; ks < KS_; ks++) s += Pb[(size_t)ks * (M_ * 80) + i];
    int m = i / 80, col = i % 80;
    if (col < DR_) {
        dbc_bf[m * KDT_ + col] = f2bf(s);
    } else if (col < DR_ + NS_) {
        bcp[m * 32 + 2 * (col - DR_)] = s;         // B_n
    } else {
        bcp[m * 32 + 2 * (col - DR_ - NS_) + 1] = s; // C_n
    }
}

// ---------------- scan pass A: per-chunk summaries (S[16] + sd scalar) ------
__global__ __launch_bounds__(256) void scan_ps_kernel(
    const float* __restrict__ dtb,     // (B*L, DI) dt
    const float* __restrict__ xcf,     // (B*L, DI) xc
    const float4* __restrict__ bcp4,   // (B*L, 8) {B0,C0,B1,C1}x4 view
    const float* __restrict__ negA,    // (DI, NS) this layer
    float* __restrict__ Sb,            // (B, NC, DI, NS)
    float* __restrict__ sdb) {         // (B, NC, DI)
    const int NDB = DI_ / 256;         // 6 d-blocks
    int bx = blockIdx.x;
    int dblk = bx % NDB;
    int c = (bx / NDB) % NC_;
    int b = bx / (NDB * NC_);
    int d = dblk * 256 + threadIdx.x;

    float A[NS_];
    #pragma unroll
    for (int n = 0; n < NS_; n++) A[n] = negA[(size_t)d * NS_ + n];
    float h[NS_];
    #pragma unroll
    for (int n = 0; n < NS_; n++) h[n] = 0.f;
    float sd = 0.f;

    size_t btbase = (size_t)(b * L_ + c * T_);
    const float* pdt = dtb + btbase * DI_ + d;
    const float* pxc = xcf + btbase * DI_ + d;
    const float4* pbc = bcp4 + btbase * 8;

    #pragma unroll
    for (int t = 0; t < T_; t++) {
        float dt = pdt[(size_t)t * DI_];
        float u  = dt * pxc[(size_t)t * DI_];
        sd += dt;
        #pragma unroll
        for (int q = 0; q < 8; q++) {
            float4 v = pbc[t * 8 + q];     // {B_2q, C_2q, B_2q+1, C_2q+1}
            float e0 = __expf(dt * A[2 * q]);
            h[2 * q] = fmaf(e0, h[2 * q], u * v.x);
            float e1 = __expf(dt * A[2 * q + 1]);
            h[2 * q + 1] = fmaf(e1, h[2 * q + 1], u * v.z);
        }
    }

    size_t o = (((size_t)b * NC_ + c) * DI_ + d) * NS_;
    #pragma unroll
    for (int n = 0; n < NS_; n++) Sb[o + n] = h[n];
    sdb[((size_t)b * NC_ + c) * DI_ + d] = sd;
}

// ---------------- scan pass B: sequential combine (P = exp(A*sd) recomputed)
__global__ __launch_bounds__(256) void scan_combine_kernel(
    const float* __restrict__ Sb, const float* __restrict__ sdb,
    const float* __restrict__ negA, float* __restrict__ hin) {
    int i = blockIdx.x * 256 + threadIdx.x;   // over B*DI*NS
    int b = i / (DI_ * NS_);
    int rem = i % (DI_ * NS_);
    int d = rem >> 4;                          // NS = 16
    float Aa = negA[rem];                      // (DI, NS) layer slice
    const size_t str = (size_t)DI_ * NS_;
    size_t o = (size_t)b * NC_ * str + rem;
    size_t osd = (size_t)b * NC_ * DI_ + d;
    float h = 0.f;
    float s = Sb[o], sd = sdb[osd];
    #pragma unroll 4
    for (int c = 0; c < NC_ - 1; c++) {
        float sn = Sb[o + str];
        float sdn = sdb[osd + DI_];
        hin[o] = h;
        h = fmaf(__expf(Aa * sd), h, s);
        s = sn; sd = sdn;
        o += str; osd += DI_;
    }
    hin[o] = h;
}

// ---------------- scan pass C: exact recurrence from hin -> yg --------------
__global__ __launch_bounds__(256) void scan_out_kernel(
    const float* __restrict__ dtb, const float* __restrict__ xcf,
    const float4* __restrict__ bcp4, const float* __restrict__ negA,
    const float* __restrict__ hin, const float* __restrict__ xz,
    const float* __restrict__ Dp, unsigned short* __restrict__ yg) {
    const int NDB = DI_ / 256;
    int bx = blockIdx.x;
    int dblk = bx % NDB;
    int c = (bx / NDB) % NC_;
    int b = bx / (NDB * NC_);
    int d = dblk * 256 + threadIdx.x;

    float A[NS_];
    #pragma unroll
    for (int n = 0; n < NS_; n++) A[n] = negA[(size_t)d * NS_ + n];
    size_t o = (((size_t)b * NC_ + c) * DI_ + d) * NS_;
    float h[NS_];
    #pragma unroll
    for (int n = 0; n < NS_; n++) h[n] = hin[o + n];
    float dpv = Dp[d];

    size_t btbase = (size_t)(b * L_ + c * T_);
    const float* pdt = dtb + btbase * DI_ + d;
    const float* pxc = xcf + btbase * DI_ + d;
    const float4* pbc = bcp4 + btbase * 8;

    #pragma unroll
    for (int t = 0; t < T_; t++) {
        float dt = pdt[(size_t)t * DI_];
        float xc = pxc[(size_t)t * DI_];
        float u = dt * xc;
        float y = 0.f;
        #pragma unroll
        for (int q = 0; q < 8; q++) {
            float4 v = pbc[t * 8 + q];     // {B_2q, C_2q, B_2q+1, C_2q+1}
            float e0 = __expf(dt * A[2 * q]);
            h[2 * q] = fmaf(e0, h[2 * q], u * v.x);
            y = fmaf(v.y, h[2 * q], y);
            float e1 = __expf(dt * A[2 * q + 1]);
            h[2 * q + 1] = fmaf(e1, h[2 * q + 1], u * v.z);
            y = fmaf(v.w, h[2 * q + 1], y);
        }
        size_t row = btbase + t;
        float zv = xz[row * (2 * DI_) + DI_ + d];
        float yy = y + xc * dpv;
        yy *= zv / (1.0f + __expf(-zv));
        yg[row * DI_ + d] = f2bf(yy);
    }
}

extern "C" void kernel_launch(void* const* d_in, const int* in_sizes, int n_in,
                              void* d_out, int out_size, void* d_ws, size_t ws_size,
                              hipStream_t stream) {
    const float* x        = (const float*)d_in[0];
    const float* ln_w     = (const float*)d_in[1];
    const float* ln_b     = (const float*)d_in[2];
    const float* in_proj  = (const float*)d_in[3];
    const float* conv_w   = (const float*)d_in[4];
    const float* conv_b   = (const float*)d_in[5];
    const float* x_proj   = (const float*)d_in[6];
    const float* dt_w     = (const float*)d_in[7];
    const float* dt_b     = (const float*)d_in[8];
    const float* A_log    = (const float*)d_in[9];
    const float* D_skip   = (const float*)d_in[10];
    const float* out_proj = (const float*)d_in[11];
    const float* fn_w     = (const float*)d_in[12];
    const float* fn_b     = (const float*)d_in[13];
    float* out = (float*)d_out;

    char* p = (char*)d_ws;
    auto alloc = [&](size_t bytes) {
        char* r = p;
        p += (bytes + 255) & ~(size_t)255;
        return (void*)r;
    };
    float* xcur = (float*)alloc((size_t)M_ * D_ * 4);
    float* res  = (float*)alloc((size_t)M_ * D_ * 4);
    unsigned short* xn = (unsigned short*)alloc((size_t)M_ * D_ * 2);
    float* xz   = (float*)alloc((size_t)M_ * 2 * DI_ * 4);
    float* dtb  = (float*)alloc((size_t)M_ * DI_ * 4);       // dt (contiguous)
    float* xcf  = (float*)alloc((size_t)M_ * DI_ * 4);       // conv+silu out
    unsigned short* dbc_bf = (unsigned short*)alloc((size_t)M_ * KDT_ * 2);
    float* bcp  = (float*)alloc((size_t)M_ * 32 * 4);        // {B,C} pairs x 16
    unsigned short* yg = (unsigned short*)alloc((size_t)M_ * DI_ * 2);
    float* Sb   = (float*)alloc((size_t)B_ * NC_ * DI_ * NS_ * 4);   // 12.6 MB
    float* sdb  = (float*)alloc((size_t)B_ * NC_ * DI_ * 4);         // 0.8 MB
    float* hin  = (float*)alloc((size_t)B_ * NC_ * DI_ * NS_ * 4);
    float* Pb   = (float*)alloc((size_t)KS_ * M_ * 80 * 4);
    float* negA = (float*)alloc((size_t)NL_ * DI_ * NS_ * 4);
    const size_t n_wi = (size_t)NL_ * 2 * DI_ * D_;   // 18.87M
    const size_t n_wo = (size_t)NL_ * D_ * DI_;       // 9.44M
    const size_t n_wx = (size_t)NL_ * 80 * DI_;       // 0.98M
    const size_t n_wdt = (size_t)NL_ * DI_ * KDT_;    // 0.79M (padded)
    unsigned short* wi_bf = (unsigned short*)alloc(n_wi * 2);
    unsigned short* wo_bf = (unsigned short*)alloc(n_wo * 2);
    unsigned short* wx_bf = (unsigned short*)alloc(n_wx * 2);
    unsigned short* wdt_bf = (unsigned short*)alloc(n_wdt * 2);

    // prep: 4096 contiguous elems per block, lane-coalesced.
    // total = 31981568 elems -> 7808 blocks exactly.
    prep_kernel<<<7808, 256, 0, stream>>>(
        in_proj, wi_bf, out_proj, wo_bf, x_proj, wx_bf,
        dt_w, wdt_bf, A_log, negA, x, xcur, res, dbc_bf);

    for (int l = 0; l < NL_; l++) {
        const float* negA_l = negA + (size_t)l * DI_ * NS_;

        ln_res_kernel<<<M_, 256, 0, stream>>>(
            xcur, res, ln_w + l * D_, ln_b + l * D_, xn);

        // xz = xn @ Wi^T   (M=2048, N=3072, K=768)  bf16 MFMA, 128x128 tiles
        gemm_bf16_t<128, 128><<<dim3((2 * DI_) / 128, M_ / 128), 256, 0, stream>>>(
            xn, wi_bf + (size_t)l * 2 * DI_ * D_, xz, M_, 2 * DI_, D_);

        // fused conv+SiLU+x_proj (split-K): writes xcf + Pb
        conv_xproj_kernel<<<dim3(KS_, M_ / 64), 256, 0, stream>>>(
            xz, conv_w + l * DI_ * KC_, conv_b + l * DI_,
            wx_bf + (size_t)l * 80 * DI_, xcf, Pb);
        xproj_reduce_kernel<<<(M_ * 80) / 256, 256, 0, stream>>>(Pb, dbc_bf, bcp);

        // dt = softplus(dbc_bf @ Wdt^T + bdt)  (M=2048, N=1536, K=64) bf16 MFMA
        dt_gemm_bf16<<<dim3(DI_ / 128, M_ / 128), 256, 0, stream>>>(
            dbc_bf, wdt_bf + (size_t)l * DI_ * KDT_, dt_b + l * DI_, dtb);

        // selective scan: summaries -> combine -> exact recurrence + output
        scan_ps_kernel<<<B_ * NC_ * (DI_ / 256), 256, 0, stream>>>(
            dtb, xcf, (const float4*)bcp, negA_l, Sb, sdb);
        scan_combine_kernel<<<(B_ * DI_ * NS_) / 256, 256, 0, stream>>>(
            Sb, sdb, negA_l, hin);
        scan_out_kernel<<<B_ * NC_ * (DI_ / 256), 256, 0, stream>>>(
            dtb, xcf, (const float4*)bcp, negA_l, hin, xz,
            D_skip + (size_t)l * DI_, yg);

        // xcur = yg @ Wo^T  (M=2048, N=768, K=1536)  bf16 MFMA, 128x64 tiles
        gemm_bf16_t<128, 64><<<dim3(D_ / 64, M_ / 128), 256, 0, stream>>>(
            yg, wo_bf + (size_t)l * D_ * DI_, xcur, M_, D_, DI_);
    }

    final_ln_kernel<<<M_, 256, 0, stream>>>(xcur, res, fn_w, fn_b, out);
}

// Round 5
// 1349.844 us; speedup vs baseline: 1.2767x; 1.0428x over previous
//
#include <hip/hip_runtime.h>
#include <math.h>

#define B_ 2
#define L_ 1024
#define D_ 768
#define NL_ 8
#define DI_ 1536
#define NS_ 16
#define DR_ 48
#define KC_ 4
#define EPS_ 1e-5f
#define M_ (B_*L_)   // 2048 rows
#define NC_ 64       // scan chunks (thread-per-channel layout)
#define T_ 16        // chunk length (NC_*T_ == L_)
#define KS_ 16       // x_proj split-K factor
#define KCH_ (DI_/KS_)   // 96 per split
#define KDT_ 64          // dt GEMM padded K (48 -> 64)

typedef short bf16x8 __attribute__((ext_vector_type(8)));
typedef float f32x4  __attribute__((ext_vector_type(4)));

// ---------------- fp32 -> bf16 (RNE) ---------------------------------------
__device__ __forceinline__ unsigned short f2bf(float f) {
    union { float f; unsigned int u; } v; v.f = f;
    unsigned int u = v.u;
    u += 0x7fffu + ((u >> 16) & 1u);
    return (unsigned short)(u >> 16);
}

__device__ __forceinline__ unsigned int pk2(float a, float b) {
    union { float f; unsigned int u; } va, vb;
    va.f = a; vb.f = b;
    unsigned int ua = va.u + (0x7fffu + ((va.u >> 16) & 1u));
    unsigned int ub = vb.u + (0x7fffu + ((vb.u >> 16) & 1u));
    return (ua >> 16) | (ub & 0xffff0000u);
}

// async global->LDS, 16B per lane; LDS dest must be wave-uniform base + lane*16
__device__ __forceinline__ void gload16(const void* g, void* l) {
    __builtin_amdgcn_global_load_lds(
        (const __attribute__((address_space(1))) void*)g,
        (__attribute__((address_space(3))) void*)l, 16, 0, 0);
}

// ---------------- prep: region-dispatched, block owns 4096 contiguous elems -
// ALL 4 loads issued before any convert/store: 4x memory-level parallelism.
__device__ __forceinline__ void cvt_blk(const float* __restrict__ s,
                                        unsigned short* __restrict__ d, int tid) {
    int o = tid * 4;
    float4 a0 = *(const float4*)&s[o];
    float4 a1 = *(const float4*)&s[o + 1024];
    float4 a2 = *(const float4*)&s[o + 2048];
    float4 a3 = *(const float4*)&s[o + 3072];
    *(uint2*)&d[o]        = (uint2){pk2(a0.x, a0.y), pk2(a0.z, a0.w)};
    *(uint2*)&d[o + 1024] = (uint2){pk2(a1.x, a1.y), pk2(a1.z, a1.w)};
    *(uint2*)&d[o + 2048] = (uint2){pk2(a2.x, a2.y), pk2(a2.z, a2.w)};
    *(uint2*)&d[o + 3072] = (uint2){pk2(a3.x, a3.y), pk2(a3.z, a3.w)};
}

__global__ __launch_bounds__(256) void prep_kernel(
    const float* __restrict__ wi, unsigned short* __restrict__ wi_bf,
    const float* __restrict__ wo, unsigned short* __restrict__ wo_bf,
    const float* __restrict__ wx, unsigned short* __restrict__ wx_bf,
    const float* __restrict__ wdt, unsigned short* __restrict__ wdt_bf,
    const float* __restrict__ A_log, float* __restrict__ negA,
    const float* __restrict__ x, float* __restrict__ xcur,
    float* __restrict__ res,
    unsigned short* __restrict__ dbc_bf) {
    const int E0 = NL_ * 2 * DI_ * D_;   // 18874368 wi   (/4096 = 4608)
    const int E1 = NL_ * D_ * DI_;       // 9437184  wo   (2304)
    const int E2 = NL_ * 80 * DI_;       // 983040   wx   (240)
    const int E3 = NL_ * DI_ * KDT_;     // 786432   wdt  (192)
    const int E4 = NL_ * DI_ * NS_;      // 196608   negA (48)
    const int E5 = M_ * D_;              // 1572864  init (384)
    int tid = threadIdx.x;
    int base = blockIdx.x * 4096;
    if (base < E0) { cvt_blk(wi + base, wi_bf + base, tid); return; }
    base -= E0;
    if (base < E1) { cvt_blk(wo + base, wo_bf + base, tid); return; }
    base -= E1;
    if (base < E2) { cvt_blk(wx + base, wx_bf + base, tid); return; }
    base -= E2;
    if (base < E3) {                     // dt_w: K padded 48 -> 64
        int off0 = base + tid * 4;       // col invariant across r (1024%64==0)
        int col = off0 & (KDT_ - 1);
        if (col < DR_) {
            float4 a0 = *(const float4*)&wdt[(size_t)((off0) >> 6) * DR_ + col];
            float4 a1 = *(const float4*)&wdt[(size_t)((off0 + 1024) >> 6) * DR_ + col];
            float4 a2 = *(const float4*)&wdt[(size_t)((off0 + 2048) >> 6) * DR_ + col];
            float4 a3 = *(const float4*)&wdt[(size_t)((off0 + 3072) >> 6) * DR_ + col];
            *(uint2*)&wdt_bf[off0]        = (uint2){pk2(a0.x, a0.y), pk2(a0.z, a0.w)};
            *(uint2*)&wdt_bf[off0 + 1024] = (uint2){pk2(a1.x, a1.y), pk2(a1.z, a1.w)};
            *(uint2*)&wdt_bf[off0 + 2048] = (uint2){pk2(a2.x, a2.y), pk2(a2.z, a2.w)};
            *(uint2*)&wdt_bf[off0 + 3072] = (uint2){pk2(a3.x, a3.y), pk2(a3.z, a3.w)};
        } else {
            uint2 z = {0u, 0u};
            *(uint2*)&wdt_bf[off0] = z;
            *(uint2*)&wdt_bf[off0 + 1024] = z;
            *(uint2*)&wdt_bf[off0 + 2048] = z;
            *(uint2*)&wdt_bf[off0 + 3072] = z;
        }
        return;
    }
    base -= E3;
    if (base < E4) {                     // negA = -exp(A_log)
        int off0 = base + tid * 4;
        float4 a0 = *(const float4*)&A_log[off0];
        float4 a1 = *(const float4*)&A_log[off0 + 1024];
        float4 a2 = *(const float4*)&A_log[off0 + 2048];
        float4 a3 = *(const float4*)&A_log[off0 + 3072];
        *(float4*)&negA[off0] = make_float4(-__expf(a0.x), -__expf(a0.y), -__expf(a0.z), -__expf(a0.w));
        *(float4*)&negA[off0 + 1024] = make_float4(-__expf(a1.x), -__expf(a1.y), -__expf(a1.z), -__expf(a1.w));
        *(float4*)&negA[off0 + 2048] = make_float4(-__expf(a2.x), -__expf(a2.y), -__expf(a2.z), -__expf(a2.w));
        *(float4*)&negA[off0 + 3072] = make_float4(-__expf(a3.x), -__expf(a3.y), -__expf(a3.z), -__expf(a3.w));
        return;
    }
    base -= E4;
    if (base < E5) {                     // xcur = x; res = 0
        int off0 = base + tid * 4;
        float4 a0 = *(const float4*)&x[off0];
        float4 a1 = *(const float4*)&x[off0 + 1024];
        float4 a2 = *(const float4*)&x[off0 + 2048];
        float4 a3 = *(const float4*)&x[off0 + 3072];
        float4 z = make_float4(0.f, 0.f, 0.f, 0.f);
        *(float4*)&xcur[off0] = a0;        *(float4*)&res[off0] = z;
        *(float4*)&xcur[off0 + 1024] = a1; *(float4*)&res[off0 + 1024] = z;
        *(float4*)&xcur[off0 + 2048] = a2; *(float4*)&res[off0 + 2048] = z;
        *(float4*)&xcur[off0 + 3072] = a3; *(float4*)&res[off0 + 3072] = z;
        return;
    }
    base -= E5;
    {                                    // zero dbc_bf pad (cols >= 48 stay 0)
        int off0 = base + tid * 4;
        uint2 z = {0u, 0u};
        *(uint2*)&dbc_bf[off0] = z;
        *(uint2*)&dbc_bf[off0 + 1024] = z;
        *(uint2*)&dbc_bf[off0 + 2048] = z;
        *(uint2*)&dbc_bf[off0 + 3072] = z;
    }
}

// ---------------- wave-wide sum (64 lanes), result broadcast ----------------
__device__ __forceinline__ float wave_sum(float v) {
    #pragma unroll
    for (int o = 32; o > 0; o >>= 1) v += __shfl_down(v, o);
    return __shfl(v, 0);
}

// ---------------- fused residual-accumulate + LayerNorm (bf16 out) ----------
// wave-per-row: no LDS, no barriers. 12 elems/lane = 3 x float4.
__global__ __launch_bounds__(256) void ln_res_kernel(
    const float* __restrict__ xcur, float* __restrict__ res,
    const float* __restrict__ w, const float* __restrict__ b,
    unsigned short* __restrict__ xn) {
    int wave = threadIdx.x >> 6, lane = threadIdx.x & 63;
    int row = blockIdx.x * 4 + wave;
    size_t base = (size_t)row * D_;
    int off = lane * 4;
    float4 v0 = *(const float4*)&xcur[base + off];
    float4 v1 = *(const float4*)&xcur[base + off + 256];
    float4 v2 = *(const float4*)&xcur[base + off + 512];
    float4 r0 = *(const float4*)&res[base + off];
    float4 r1 = *(const float4*)&res[base + off + 256];
    float4 r2 = *(const float4*)&res[base + off + 512];
    r0.x += v0.x; r0.y += v0.y; r0.z += v0.z; r0.w += v0.w;
    r1.x += v1.x; r1.y += v1.y; r1.z += v1.z; r1.w += v1.w;
    r2.x += v2.x; r2.y += v2.y; r2.z += v2.z; r2.w += v2.w;
    *(float4*)&res[base + off]       = r0;
    *(float4*)&res[base + off + 256] = r1;
    *(float4*)&res[base + off + 512] = r2;
    float s = (v0.x + v0.y + v0.z + v0.w) + (v1.x + v1.y + v1.z + v1.w)
            + (v2.x + v2.y + v2.z + v2.w);
    float mu = wave_sum(s) * (1.0f / D_);
    float4 d0 = make_float4(v0.x - mu, v0.y - mu, v0.z - mu, v0.w - mu);
    float4 d1 = make_float4(v1.x - mu, v1.y - mu, v1.z - mu, v1.w - mu);
    float4 d2 = make_float4(v2.x - mu, v2.y - mu, v2.z - mu, v2.w - mu);
    float sv = d0.x * d0.x + d0.y * d0.y + d0.z * d0.z + d0.w * d0.w
             + d1.x * d1.x + d1.y * d1.y + d1.z * d1.z + d1.w * d1.w
             + d2.x * d2.x + d2.y * d2.y + d2.z * d2.z + d2.w * d2.w;
    float var = wave_sum(sv) * (1.0f / D_);
    float rs = rsqrtf(var + EPS_);
    float4 w0 = *(const float4*)&w[off];
    float4 w1 = *(const float4*)&w[off + 256];
    float4 w2 = *(const float4*)&w[off + 512];
    float4 b0 = *(const float4*)&b[off];
    float4 b1 = *(const float4*)&b[off + 256];
    float4 b2 = *(const float4*)&b[off + 512];
    *(uint2*)&xn[base + off] = (uint2){
        pk2(d0.x * rs * w0.x + b0.x, d0.y * rs * w0.y + b0.y),
        pk2(d0.z * rs * w0.z + b0.z, d0.w * rs * w0.w + b0.w)};
    *(uint2*)&xn[base + off + 256] = (uint2){
        pk2(d1.x * rs * w1.x + b1.x, d1.y * rs * w1.y + b1.y),
        pk2(d1.z * rs * w1.z + b1.z, d1.w * rs * w1.w + b1.w)};
    *(uint2*)&xn[base + off + 512] = (uint2){
        pk2(d2.x * rs * w2.x + b2.x, d2.y * rs * w2.y + b2.y),
        pk2(d2.z * rs * w2.z + b2.z, d2.w * rs * w2.w + b2.w)};
}

// ---------------- final LN: out = LN(xcur + res), wave-per-row --------------
__global__ __launch_bounds__(256) void final_ln_kernel(
    const float* __restrict__ xcur, const float* __restrict__ res,
    const float* __restrict__ w, const float* __restrict__ b,
    float* __restrict__ out) {
    int wave = threadIdx.x >> 6, lane = threadIdx.x & 63;
    int row = blockIdx.x * 4 + wave;
    size_t base = (size_t)row * D_;
    int off = lane * 4;
    float4 v0 = *(const float4*)&xcur[base + off];
    float4 v1 = *(const float4*)&xcur[base + off + 256];
    float4 v2 = *(const float4*)&xcur[base + off + 512];
    float4 r0 = *(const float4*)&res[base + off];
    float4 r1 = *(const float4*)&res[base + off + 256];
    float4 r2 = *(const float4*)&res[base + off + 512];
    v0.x += r0.x; v0.y += r0.y; v0.z += r0.z; v0.w += r0.w;
    v1.x += r1.x; v1.y += r1.y; v1.z += r1.z; v1.w += r1.w;
    v2.x += r2.x; v2.y += r2.y; v2.z += r2.z; v2.w += r2.w;
    float s = (v0.x + v0.y + v0.z + v0.w) + (v1.x + v1.y + v1.z + v1.w)
            + (v2.x + v2.y + v2.z + v2.w);
    float mu = wave_sum(s) * (1.0f / D_);
    float4 d0 = make_float4(v0.x - mu, v0.y - mu, v0.z - mu, v0.w - mu);
    float4 d1 = make_float4(v1.x - mu, v1.y - mu, v1.z - mu, v1.w - mu);
    float4 d2 = make_float4(v2.x - mu, v2.y - mu, v2.z - mu, v2.w - mu);
    float sv = d0.x * d0.x + d0.y * d0.y + d0.z * d0.z + d0.w * d0.w
             + d1.x * d1.x + d1.y * d1.y + d1.z * d1.z + d1.w * d1.w
             + d2.x * d2.x + d2.y * d2.y + d2.z * d2.z + d2.w * d2.w;
    float var = wave_sum(sv) * (1.0f / D_);
    float rs = rsqrtf(var + EPS_);
    float4 w0 = *(const float4*)&w[off];
    float4 w1 = *(const float4*)&w[off + 256];
    float4 w2 = *(const float4*)&w[off + 512];
    float4 b0 = *(const float4*)&b[off];
    float4 b1 = *(const float4*)&b[off + 256];
    float4 b2 = *(const float4*)&b[off + 512];
    *(float4*)&out[base + off] = make_float4(
        d0.x * rs * w0.x + b0.x, d0.y * rs * w0.y + b0.y,
        d0.z * rs * w0.z + b0.z, d0.w * rs * w0.w + b0.w);
    *(float4*)&out[base + off + 256] = make_float4(
        d1.x * rs * w1.x + b1.x, d1.y * rs * w1.y + b1.y,
        d1.z * rs * w1.z + b1.z, d1.w * rs * w1.w + b1.w);
    *(float4*)&out[base + off + 512] = make_float4(
        d2.x * rs * w2.x + b2.x, d2.y * rs * w2.y + b2.y,
        d2.z * rs * w2.z + b2.z, d2.w * rs * w2.w + b2.w);
}

// ---------------- bf16 MFMA GEMM: C[M,N] = A[M,K] * W[N,K]^T ---------------
template <int BM, int BN>
__global__ __launch_bounds__(256) void gemm_bf16_t(
    const unsigned short* __restrict__ A,   // M x K bf16 row-major
    const unsigned short* __restrict__ W,   // N x K bf16 row-major
    float* __restrict__ C, int M, int N, int K) {
    constexpr int FM = BM / 32;
    constexpr int FN = BN / 32;
    constexpr int NLD = (BM + BN) / 64;
    __shared__ unsigned short sA[BM * 32];
    __shared__ unsigned short sW[BN * 32];
    int bm = blockIdx.y * BM, bn = blockIdx.x * BN;
    int tid = threadIdx.x;
    int wave = tid >> 6, lane = tid & 63;
    int wrow = (wave & 1) * (BM / 2), wcol = (wave >> 1) * (BN / 2);
    int quad = lane >> 4, r16 = lane & 15;
    f32x4 acc[FM][FN];
    #pragma unroll
    for (int i = 0; i < FM; i++)
        #pragma unroll
        for (int j = 0; j < FN; j++)
            acc[i][j] = (f32x4){0.f, 0.f, 0.f, 0.f};

    for (int k0 = 0; k0 < K; k0 += 32) {
        #pragma unroll
        for (int r = 0; r < NLD; r++) {
            if (r < BM / 64) {
                int j = r * 256 + tid;
                gload16(&A[(size_t)(bm + (j >> 2)) * K + k0 + (j & 3) * 8],
                        &sA[(r * 256 + wave * 64) * 8]);
            } else {
                int j = (r - BM / 64) * 256 + tid;
                gload16(&W[(size_t)(bn + (j >> 2)) * K + k0 + (j & 3) * 8],
                        &sW[((r - BM / 64) * 256 + wave * 64) * 8]);
            }
        }
        __syncthreads();
        bf16x8 af[FM], wf[FN];
        #pragma unroll
        for (int i = 0; i < FM; i++)
            af[i] = *(const bf16x8*)&sA[(wrow + i * 16 + r16) * 32 + quad * 8];
        #pragma unroll
        for (int j = 0; j < FN; j++)
            wf[j] = *(const bf16x8*)&sW[(wcol + j * 16 + r16) * 32 + quad * 8];
        #pragma unroll
        for (int i = 0; i < FM; i++)
            #pragma unroll
            for (int j = 0; j < FN; j++)
                acc[i][j] = __builtin_amdgcn_mfma_f32_16x16x32_bf16(
                    af[i], wf[j], acc[i][j], 0, 0, 0);
        __syncthreads();
    }
    #pragma unroll
    for (int i = 0; i < FM; i++) {
        #pragma unroll
        for (int j = 0; j < FN; j++) {
            int col = bn + wcol + j * 16 + r16;
            #pragma unroll
            for (int reg = 0; reg < 4; reg++) {
                int row = bm + wrow + i * 16 + quad * 4 + reg;
                C[(size_t)row * N + col] = acc[i][j][reg];
            }
        }
    }
}

// ---------------- dt GEMM bf16 MFMA (M=2048, N=DI, K=64 padded) -------------
__global__ __launch_bounds__(256) void dt_gemm_bf16(
    const unsigned short* __restrict__ A,
    const unsigned short* __restrict__ W,
    const float* __restrict__ bias,
    float* __restrict__ dtb) {
    __shared__ unsigned short sA[128 * 32];
    __shared__ unsigned short sW[128 * 32];
    int bm = blockIdx.y * 128, bn = blockIdx.x * 128;
    int tid = threadIdx.x;
    int wave = tid >> 6, lane = tid & 63;
    int wrow = (wave & 1) * 64, wcol = (wave >> 1) * 64;
    int quad = lane >> 4, r16 = lane & 15;
    f32x4 acc[4][4];
    #pragma unroll
    for (int i = 0; i < 4; i++)
        #pragma unroll
        for (int j = 0; j < 4; j++)
            acc[i][j] = (f32x4){0.f, 0.f, 0.f, 0.f};

    #pragma unroll
    for (int k0 = 0; k0 < KDT_; k0 += 32) {
        #pragma unroll
        for (int r = 0; r < 4; r++) {
            if (r < 2) {
                int j = r * 256 + tid;
                gload16(&A[(size_t)(bm + (j >> 2)) * KDT_ + k0 + (j & 3) * 8],
                        &sA[(r * 256 + wave * 64) * 8]);
            } else {
                int j = (r - 2) * 256 + tid;
                gload16(&W[(size_t)(bn + (j >> 2)) * KDT_ + k0 + (j & 3) * 8],
                        &sW[((r - 2) * 256 + wave * 64) * 8]);
            }
        }
        __syncthreads();
        bf16x8 af[4], wf[4];
        #pragma unroll
        for (int i = 0; i < 4; i++)
            af[i] = *(const bf16x8*)&sA[(wrow + i * 16 + r16) * 32 + quad * 8];
        #pragma unroll
        for (int j = 0; j < 4; j++)
            wf[j] = *(const bf16x8*)&sW[(wcol + j * 16 + r16) * 32 + quad * 8];
        #pragma unroll
        for (int i = 0; i < 4; i++)
            #pragma unroll
            for (int j = 0; j < 4; j++)
                acc[i][j] = __builtin_amdgcn_mfma_f32_16x16x32_bf16(
                    af[i], wf[j], acc[i][j], 0, 0, 0);
        __syncthreads();
    }
    #pragma unroll
    for (int i = 0; i < 4; i++) {
        #pragma unroll
        for (int j = 0; j < 4; j++) {
            int col = bn + wcol + j * 16 + r16;
            float bv = bias[col];
            #pragma unroll
            for (int reg = 0; reg < 4; reg++) {
                int row = bm + wrow + i * 16 + quad * 4 + reg;
                float v = acc[i][j][reg] + bv;
                v = (v > 20.f) ? v : log1pf(__expf(v));
                dtb[(size_t)row * DI_ + col] = v;
            }
        }
    }
}

// ---------------- fused conv+SiLU+x_proj GEMM (split-K over ks) -------------
__global__ __launch_bounds__(256) void conv_xproj_kernel(
    const float* __restrict__ xz,
    const float* __restrict__ cw,
    const float* __restrict__ cb,
    const unsigned short* __restrict__ W,
    float* __restrict__ xcf,
    float* __restrict__ Pb) {
    __shared__ float sxz[67 * 96];
    __shared__ unsigned short sxcb[64 * 104];
    __shared__ float scw[96 * 4];
    __shared__ float scb[96];
    unsigned short* sW = (unsigned short*)sxz;

    int ks = blockIdx.x;
    int bm = blockIdx.y * 64;
    int tid = threadIdx.x;
    int b = bm >> 10, t0 = bm & (L_ - 1);
    int dbase = ks * KCH_;

    if (tid < 96) {
        int d = dbase + tid;
        *(float4*)&scw[tid * 4] = *(const float4*)&cw[d * 4];
        scb[tid] = cb[d];
    }
    for (int j = tid; j < 67 * 24; j += 256) {
        int r = j / 24, c4 = (j % 24) * 4;
        int tt = t0 + r - 3;
        float4 v = make_float4(0.f, 0.f, 0.f, 0.f);
        if (tt >= 0)
            v = *(const float4*)&xz[((size_t)(b * L_ + tt)) * (2 * DI_) + dbase + c4];
        *(float4*)&sxz[r * 96 + c4] = v;
    }
    __syncthreads();
    for (int j = tid; j < 64 * 96; j += 256) {
        int r = j / 96, c = j % 96;
        float acc = scb[c];
        #pragma unroll
        for (int k = 0; k < KC_; k++)
            acc = fmaf(scw[c * 4 + k], sxz[(r + k) * 96 + c], acc);
        float v = acc / (1.0f + __expf(-acc));
        xcf[(size_t)(bm + r) * DI_ + dbase + c] = v;
        sxcb[r * 104 + c] = f2bf(v);
    }
    __syncthreads();
    for (int j = tid; j < 80 * 12; j += 256) {
        int row = j / 12, c16 = (j % 12) * 8;
        *(uint4*)&sW[row * 104 + c16] =
            *(const uint4*)&W[(size_t)row * DI_ + dbase + c16];
    }
    __syncthreads();
    int wave = tid >> 6, lane = tid & 63;
    int quad = lane >> 4, r16 = lane & 15;
    f32x4 acc[5];
    #pragma unroll
    for (int j = 0; j < 5; j++) acc[j] = (f32x4){0.f, 0.f, 0.f, 0.f};
    #pragma unroll
    for (int kk = 0; kk < 3; kk++) {
        bf16x8 af = *(const bf16x8*)&sxcb[(wave * 16 + r16) * 104 + kk * 32 + quad * 8];
        #pragma unroll
        for (int j = 0; j < 5; j++) {
            bf16x8 wf = *(const bf16x8*)&sW[(j * 16 + r16) * 104 + kk * 32 + quad * 8];
            acc[j] = __builtin_amdgcn_mfma_f32_16x16x32_bf16(af, wf, acc[j], 0, 0, 0);
        }
    }
    #pragma unroll
    for (int j = 0; j < 5; j++) {
        int col = j * 16 + r16;
        #pragma unroll
        for (int reg = 0; reg < 4; reg++) {
            int row = bm + wave * 16 + quad * 4 + reg;
            Pb[((size_t)ks * M_ + row) * 80 + col] = acc[j][reg];
        }
    }
}

// reduce split-K partials; scatter into dbc_bf (M x 64 bf16) and packed BC
__global__ void xproj_reduce_kernel(const float* __restrict__ Pb,
                                    unsigned short* __restrict__ dbc_bf,
                                    float* __restrict__ bcp) {
    int i = blockIdx.x * 256 + threadIdx.x;   // over M_*80
    float s = 0.f;
    #pragma unroll
    for (int ks = 0; ks < KS_; ks++) s += Pb[(size_t)ks * (M_ * 80) + i];
    int m = i / 80, col = i % 80;
    if (col < DR_) {
        dbc_bf[m * KDT_ + col] = f2bf(s);
    } else if (col < DR_ + NS_) {
        bcp[m * 32 + 2 * (col - DR_)] = s;         // B_n
    } else {
        bcp[m * 32 + 2 * (col - DR_ - NS_) + 1] = s; // C_n
    }
}

// ---------------- scan pass A: per-chunk summaries (S[16] + sd scalar) ------
__global__ __launch_bounds__(256) void scan_ps_kernel(
    const float* __restrict__ dtb,
    const float* __restrict__ xcf,
    const float4* __restrict__ bcp4,
    const float* __restrict__ negA,
    float* __restrict__ Sb,
    float* __restrict__ sdb) {
    const int NDB = DI_ / 256;
    int bx = blockIdx.x;
    int dblk = bx % NDB;
    int c = (bx / NDB) % NC_;
    int b = bx / (NDB * NC_);
    int d = dblk * 256 + threadIdx.x;

    float A[NS_];
    #pragma unroll
    for (int n = 0; n < NS_; n++) A[n] = negA[(size_t)d * NS_ + n];
    float h[NS_];
    #pragma unroll
    for (int n = 0; n < NS_; n++) h[n] = 0.f;
    float sd = 0.f;

    size_t btbase = (size_t)(b * L_ + c * T_);
    const float* pdt = dtb + btbase * DI_ + d;
    const float* pxc = xcf + btbase * DI_ + d;
    const float4* pbc = bcp4 + btbase * 8;

    #pragma unroll
    for (int t = 0; t < T_; t++) {
        float dt = pdt[(size_t)t * DI_];
        float u  = dt * pxc[(size_t)t * DI_];
        sd += dt;
        #pragma unroll
        for (int q = 0; q < 8; q++) {
            float4 v = pbc[t * 8 + q];
            float e0 = __expf(dt * A[2 * q]);
            h[2 * q] = fmaf(e0, h[2 * q], u * v.x);
            float e1 = __expf(dt * A[2 * q + 1]);
            h[2 * q + 1] = fmaf(e1, h[2 * q + 1], u * v.z);
        }
    }

    size_t o = (((size_t)b * NC_ + c) * DI_ + d) * NS_;
    #pragma unroll
    for (int n = 0; n < NS_; n++) Sb[o + n] = h[n];
    sdb[((size_t)b * NC_ + c) * DI_ + d] = sd;
}

// ---------------- scan pass B: sequential combine, 4-deep pipeline ----------
// 64-thread blocks -> 768 blocks (full CU spread); statically-named prefetch
// registers (no runtime-indexed arrays -> no scratch).
__global__ __launch_bounds__(64) void scan_combine_kernel(
    const float* __restrict__ Sb, const float* __restrict__ sdb,
    const float* __restrict__ negA, float* __restrict__ hin) {
    int i = blockIdx.x * 64 + threadIdx.x;    // over B*DI*NS
    int b = i / (DI_ * NS_);
    int rem = i % (DI_ * NS_);
    int d = rem >> 4;                          // NS = 16
    float Aa = negA[rem];
    const size_t str = (size_t)DI_ * NS_;
    size_t o = (size_t)b * NC_ * str + rem;
    size_t osd = (size_t)b * NC_ * DI_ + d;
    float h = 0.f;
    // prologue: 4 chunk-summaries in flight
    float s0 = Sb[o],           sd0 = sdb[osd];
    float s1 = Sb[o + str],     sd1 = sdb[osd + DI_];
    float s2 = Sb[o + 2 * str], sd2 = sdb[osd + 2 * DI_];
    float s3 = Sb[o + 3 * str], sd3 = sdb[osd + 3 * DI_];
    for (int c = 0; c < NC_ - 4; c += 4) {     // 60 iters, 15 passes
        float n0 = Sb[o + 4 * str], nd0 = sdb[osd + 4 * DI_];
        float n1 = Sb[o + 5 * str], nd1 = sdb[osd + 5 * DI_];
        float n2 = Sb[o + 6 * str], nd2 = sdb[osd + 6 * DI_];
        float n3 = Sb[o + 7 * str], nd3 = sdb[osd + 7 * DI_];
        hin[o] = h;           h = fmaf(__expf(Aa * sd0), h, s0);
        hin[o + str] = h;     h = fmaf(__expf(Aa * sd1), h, s1);
        hin[o + 2 * str] = h; h = fmaf(__expf(Aa * sd2), h, s2);
        hin[o + 3 * str] = h; h = fmaf(__expf(Aa * sd3), h, s3);
        s0 = n0; sd0 = nd0; s1 = n1; sd1 = nd1;
        s2 = n2; sd2 = nd2; s3 = n3; sd3 = nd3;
        o += 4 * str; osd += 4 * DI_;
    }
    hin[o] = h;           h = fmaf(__expf(Aa * sd0), h, s0);
    hin[o + str] = h;     h = fmaf(__expf(Aa * sd1), h, s1);
    hin[o + 2 * str] = h; h = fmaf(__expf(Aa * sd2), h, s2);
    hin[o + 3 * str] = h;
}

// ---------------- scan pass C: exact recurrence from hin -> yg --------------
__global__ __launch_bounds__(256) void scan_out_kernel(
    const float* __restrict__ dtb, const float* __restrict__ xcf,
    const float4* __restrict__ bcp4, const float* __restrict__ negA,
    const float* __restrict__ hin, const float* __restrict__ xz,
    const float* __restrict__ Dp, unsigned short* __restrict__ yg) {
    const int NDB = DI_ / 256;
    int bx = blockIdx.x;
    int dblk = bx % NDB;
    int c = (bx / NDB) % NC_;
    int b = bx / (NDB * NC_);
    int d = dblk * 256 + threadIdx.x;

    float A[NS_];
    #pragma unroll
    for (int n = 0; n < NS_; n++) A[n] = negA[(size_t)d * NS_ + n];
    size_t o = (((size_t)b * NC_ + c) * DI_ + d) * NS_;
    float h[NS_];
    #pragma unroll
    for (int n = 0; n < NS_; n++) h[n] = hin[o + n];
    float dpv = Dp[d];

    size_t btbase = (size_t)(b * L_ + c * T_);
    const float* pdt = dtb + btbase * DI_ + d;
    const float* pxc = xcf + btbase * DI_ + d;
    const float4* pbc = bcp4 + btbase * 8;

    #pragma unroll
    for (int t = 0; t < T_; t++) {
        float dt = pdt[(size_t)t * DI_];
        float xc = pxc[(size_t)t * DI_];
        float u = dt * xc;
        float y = 0.f;
        #pragma unroll
        for (int q = 0; q < 8; q++) {
            float4 v = pbc[t * 8 + q];
            float e0 = __expf(dt * A[2 * q]);
            h[2 * q] = fmaf(e0, h[2 * q], u * v.x);
            y = fmaf(v.y, h[2 * q], y);
            float e1 = __expf(dt * A[2 * q + 1]);
            h[2 * q + 1] = fmaf(e1, h[2 * q + 1], u * v.z);
            y = fmaf(v.w, h[2 * q + 1], y);
        }
        size_t row = btbase + t;
        float zv = xz[row * (2 * DI_) + DI_ + d];
        float yy = y + xc * dpv;
        yy *= zv / (1.0f + __expf(-zv));
        yg[row * DI_ + d] = f2bf(yy);
    }
}

extern "C" void kernel_launch(void* const* d_in, const int* in_sizes, int n_in,
                              void* d_out, int out_size, void* d_ws, size_t ws_size,
                              hipStream_t stream) {
    const float* x        = (const float*)d_in[0];
    const float* ln_w     = (const float*)d_in[1];
    const float* ln_b     = (const float*)d_in[2];
    const float* in_proj  = (const float*)d_in[3];
    const float* conv_w   = (const float*)d_in[4];
    const float* conv_b   = (const float*)d_in[5];
    const float* x_proj   = (const float*)d_in[6];
    const float* dt_w     = (const float*)d_in[7];
    const float* dt_b     = (const float*)d_in[8];
    const float* A_log    = (const float*)d_in[9];
    const float* D_skip   = (const float*)d_in[10];
    const float* out_proj = (const float*)d_in[11];
    const float* fn_w     = (const float*)d_in[12];
    const float* fn_b     = (const float*)d_in[13];
    float* out = (float*)d_out;

    char* p = (char*)d_ws;
    auto alloc = [&](size_t bytes) {
        char* r = p;
        p += (bytes + 255) & ~(size_t)255;
        return (void*)r;
    };
    float* xcur = (float*)alloc((size_t)M_ * D_ * 4);
    float* res  = (float*)alloc((size_t)M_ * D_ * 4);
    unsigned short* xn = (unsigned short*)alloc((size_t)M_ * D_ * 2);
    float* xz   = (float*)alloc((size_t)M_ * 2 * DI_ * 4);
    float* dtb  = (float*)alloc((size_t)M_ * DI_ * 4);
    float* xcf  = (float*)alloc((size_t)M_ * DI_ * 4);
    unsigned short* dbc_bf = (unsigned short*)alloc((size_t)M_ * KDT_ * 2);
    float* bcp  = (float*)alloc((size_t)M_ * 32 * 4);
    unsigned short* yg = (unsigned short*)alloc((size_t)M_ * DI_ * 2);
    float* Sb   = (float*)alloc((size_t)B_ * NC_ * DI_ * NS_ * 4);
    float* sdb  = (float*)alloc((size_t)B_ * NC_ * DI_ * 4);
    float* hin  = (float*)alloc((size_t)B_ * NC_ * DI_ * NS_ * 4);
    float* Pb   = (float*)alloc((size_t)KS_ * M_ * 80 * 4);
    float* negA = (float*)alloc((size_t)NL_ * DI_ * NS_ * 4);
    const size_t n_wi = (size_t)NL_ * 2 * DI_ * D_;
    const size_t n_wo = (size_t)NL_ * D_ * DI_;
    const size_t n_wx = (size_t)NL_ * 80 * DI_;
    const size_t n_wdt = (size_t)NL_ * DI_ * KDT_;
    unsigned short* wi_bf = (unsigned short*)alloc(n_wi * 2);
    unsigned short* wo_bf = (unsigned short*)alloc(n_wo * 2);
    unsigned short* wx_bf = (unsigned short*)alloc(n_wx * 2);
    unsigned short* wdt_bf = (unsigned short*)alloc(n_wdt * 2);

    // prep: 4096 contiguous elems per block, 4 loads in flight per thread.
    prep_kernel<<<7808, 256, 0, stream>>>(
        in_proj, wi_bf, out_proj, wo_bf, x_proj, wx_bf,
        dt_w, wdt_bf, A_log, negA, x, xcur, res, dbc_bf);

    for (int l = 0; l < NL_; l++) {
        const float* negA_l = negA + (size_t)l * DI_ * NS_;

        ln_res_kernel<<<M_ / 4, 256, 0, stream>>>(
            xcur, res, ln_w + l * D_, ln_b + l * D_, xn);

        gemm_bf16_t<128, 128><<<dim3((2 * DI_) / 128, M_ / 128), 256, 0, stream>>>(
            xn, wi_bf + (size_t)l * 2 * DI_ * D_, xz, M_, 2 * DI_, D_);

        conv_xproj_kernel<<<dim3(KS_, M_ / 64), 256, 0, stream>>>(
            xz, conv_w + l * DI_ * KC_, conv_b + l * DI_,
            wx_bf + (size_t)l * 80 * DI_, xcf, Pb);
        xproj_reduce_kernel<<<(M_ * 80) / 256, 256, 0, stream>>>(Pb, dbc_bf, bcp);

        dt_gemm_bf16<<<dim3(DI_ / 128, M_ / 128), 256, 0, stream>>>(
            dbc_bf, wdt_bf + (size_t)l * DI_ * KDT_, dt_b + l * DI_, dtb);

        scan_ps_kernel<<<B_ * NC_ * (DI_ / 256), 256, 0, stream>>>(
            dtb, xcf, (const float4*)bcp, negA_l, Sb, sdb);
        scan_combine_kernel<<<(B_ * DI_ * NS_) / 64, 64, 0, stream>>>(
            Sb, sdb, negA_l, hin);
        scan_out_kernel<<<B_ * NC_ * (DI_ / 256), 256, 0, stream>>>(
            dtb, xcf, (const float4*)bcp, negA_l, hin, xz,
            D_skip + (size_t)l * DI_, yg);

        gemm_bf16_t<128, 64><<<dim3(D_ / 64, M_ / 128), 256, 0, stream>>>(
            yg, wo_bf + (size_t)l * D_ * DI_, xcur, M_, D_, DI_);
    }

    final_ln_kernel<<<M_ / 4, 256, 0, stream>>>(xcur, res, fn_w, fn_b, out);
}

// Round 7
// 1280.699 us; speedup vs baseline: 1.3456x; 1.0540x over previous
//
#include <hip/hip_runtime.h>
#include <math.h>

#define B_ 2
#define L_ 1024
#define D_ 768
#define NL_ 8
#define DI_ 1536
#define NS_ 16
#define DR_ 48
#define KC_ 4
#define EPS_ 1e-5f
#define M_ (B_*L_)   // 2048 rows
#define NC_ 32       // scan chunks
#define T_ 32        // chunk length (NC_*T_ == L_)
#define KS_ 16       // x_proj split-K factor
#define KCH_ (DI_/KS_)   // 96 per split
#define KDT_ 64          // dt GEMM padded K (48 -> 64)

typedef short bf16x8 __attribute__((ext_vector_type(8)));
typedef float f32x4  __attribute__((ext_vector_type(4)));

// ---------------- fp32 -> bf16 (RNE) ---------------------------------------
__device__ __forceinline__ unsigned short f2bf(float f) {
    union { float f; unsigned int u; } v; v.f = f;
    unsigned int u = v.u;
    u += 0x7fffu + ((u >> 16) & 1u);
    return (unsigned short)(u >> 16);
}

__device__ __forceinline__ unsigned int pk2(float a, float b) {
    union { float f; unsigned int u; } va, vb;
    va.f = a; vb.f = b;
    unsigned int ua = va.u + (0x7fffu + ((va.u >> 16) & 1u));
    unsigned int ub = vb.u + (0x7fffu + ((vb.u >> 16) & 1u));
    return (ua >> 16) | (ub & 0xffff0000u);
}

// async global->LDS, 16B per lane; LDS dest must be wave-uniform base + lane*16
__device__ __forceinline__ void gload16(const void* g, void* l) {
    __builtin_amdgcn_global_load_lds(
        (const __attribute__((address_space(1))) void*)g,
        (__attribute__((address_space(3))) void*)l, 16, 0, 0);
}

// ---------------- prep (clock-ramp-bound; structure frozen) -----------------
__device__ __forceinline__ void cvt_blk(const float* __restrict__ s,
                                        unsigned short* __restrict__ d, int tid) {
    int o = tid * 4;
    float4 a0 = *(const float4*)&s[o];
    float4 a1 = *(const float4*)&s[o + 1024];
    float4 a2 = *(const float4*)&s[o + 2048];
    float4 a3 = *(const float4*)&s[o + 3072];
    *(uint2*)&d[o]        = (uint2){pk2(a0.x, a0.y), pk2(a0.z, a0.w)};
    *(uint2*)&d[o + 1024] = (uint2){pk2(a1.x, a1.y), pk2(a1.z, a1.w)};
    *(uint2*)&d[o + 2048] = (uint2){pk2(a2.x, a2.y), pk2(a2.z, a2.w)};
    *(uint2*)&d[o + 3072] = (uint2){pk2(a3.x, a3.y), pk2(a3.z, a3.w)};
}

__global__ __launch_bounds__(256) void prep_kernel(
    const float* __restrict__ wi, unsigned short* __restrict__ wi_bf,
    const float* __restrict__ wo, unsigned short* __restrict__ wo_bf,
    const float* __restrict__ wx, unsigned short* __restrict__ wx_bf,
    const float* __restrict__ wdt, unsigned short* __restrict__ wdt_bf,
    const float* __restrict__ A_log, float* __restrict__ negA,
    const float* __restrict__ x, float* __restrict__ xcur,
    float* __restrict__ res,
    unsigned short* __restrict__ dbc_bf) {
    const int E0 = NL_ * 2 * DI_ * D_;   // 18874368 wi
    const int E1 = NL_ * D_ * DI_;       // 9437184  wo
    const int E2 = NL_ * 80 * DI_;       // 983040   wx
    const int E3 = NL_ * DI_ * KDT_;     // 786432   wdt
    const int E4 = NL_ * DI_ * NS_;      // 196608   negA
    const int E5 = M_ * D_;              // 1572864  init
    int tid = threadIdx.x;
    int base = blockIdx.x * 4096;
    if (base < E0) { cvt_blk(wi + base, wi_bf + base, tid); return; }
    base -= E0;
    if (base < E1) { cvt_blk(wo + base, wo_bf + base, tid); return; }
    base -= E1;
    if (base < E2) { cvt_blk(wx + base, wx_bf + base, tid); return; }
    base -= E2;
    if (base < E3) {                     // dt_w: K padded 48 -> 64
        int off0 = base + tid * 4;
        int col = off0 & (KDT_ - 1);
        if (col < DR_) {
            float4 a0 = *(const float4*)&wdt[(size_t)((off0) >> 6) * DR_ + col];
            float4 a1 = *(const float4*)&wdt[(size_t)((off0 + 1024) >> 6) * DR_ + col];
            float4 a2 = *(const float4*)&wdt[(size_t)((off0 + 2048) >> 6) * DR_ + col];
            float4 a3 = *(const float4*)&wdt[(size_t)((off0 + 3072) >> 6) * DR_ + col];
            *(uint2*)&wdt_bf[off0]        = (uint2){pk2(a0.x, a0.y), pk2(a0.z, a0.w)};
            *(uint2*)&wdt_bf[off0 + 1024] = (uint2){pk2(a1.x, a1.y), pk2(a1.z, a1.w)};
            *(uint2*)&wdt_bf[off0 + 2048] = (uint2){pk2(a2.x, a2.y), pk2(a2.z, a2.w)};
            *(uint2*)&wdt_bf[off0 + 3072] = (uint2){pk2(a3.x, a3.y), pk2(a3.z, a3.w)};
        } else {
            uint2 z = {0u, 0u};
            *(uint2*)&wdt_bf[off0] = z;
            *(uint2*)&wdt_bf[off0 + 1024] = z;
            *(uint2*)&wdt_bf[off0 + 2048] = z;
            *(uint2*)&wdt_bf[off0 + 3072] = z;
        }
        return;
    }
    base -= E3;
    if (base < E4) {                     // negA = -exp(A_log)
        int off0 = base + tid * 4;
        float4 a0 = *(const float4*)&A_log[off0];
        float4 a1 = *(const float4*)&A_log[off0 + 1024];
        float4 a2 = *(const float4*)&A_log[off0 + 2048];
        float4 a3 = *(const float4*)&A_log[off0 + 3072];
        *(float4*)&negA[off0] = make_float4(-__expf(a0.x), -__expf(a0.y), -__expf(a0.z), -__expf(a0.w));
        *(float4*)&negA[off0 + 1024] = make_float4(-__expf(a1.x), -__expf(a1.y), -__expf(a1.z), -__expf(a1.w));
        *(float4*)&negA[off0 + 2048] = make_float4(-__expf(a2.x), -__expf(a2.y), -__expf(a2.z), -__expf(a2.w));
        *(float4*)&negA[off0 + 3072] = make_float4(-__expf(a3.x), -__expf(a3.y), -__expf(a3.z), -__expf(a3.w));
        return;
    }
    base -= E4;
    if (base < E5) {                     // xcur = x; res = 0
        int off0 = base + tid * 4;
        float4 a0 = *(const float4*)&x[off0];
        float4 a1 = *(const float4*)&x[off0 + 1024];
        float4 a2 = *(const float4*)&x[off0 + 2048];
        float4 a3 = *(const float4*)&x[off0 + 3072];
        float4 z = make_float4(0.f, 0.f, 0.f, 0.f);
        *(float4*)&xcur[off0] = a0;        *(float4*)&res[off0] = z;
        *(float4*)&xcur[off0 + 1024] = a1; *(float4*)&res[off0 + 1024] = z;
        *(float4*)&xcur[off0 + 2048] = a2; *(float4*)&res[off0 + 2048] = z;
        *(float4*)&xcur[off0 + 3072] = a3; *(float4*)&res[off0 + 3072] = z;
        return;
    }
    base -= E5;
    {                                    // zero dbc_bf pad (cols >= 48 stay 0)
        int off0 = base + tid * 4;
        uint2 z = {0u, 0u};
        *(uint2*)&dbc_bf[off0] = z;
        *(uint2*)&dbc_bf[off0 + 1024] = z;
        *(uint2*)&dbc_bf[off0 + 2048] = z;
        *(uint2*)&dbc_bf[off0 + 3072] = z;
    }
}

// ---------------- wave-wide sum (64 lanes), result broadcast ----------------
__device__ __forceinline__ float wave_sum(float v) {
    #pragma unroll
    for (int o = 32; o > 0; o >>= 1) v += __shfl_down(v, o);
    return __shfl(v, 0);
}

// ---------------- fused residual-accumulate + LayerNorm (bf16 out) ----------
__global__ __launch_bounds__(256) void ln_res_kernel(
    const float* __restrict__ xcur, float* __restrict__ res,
    const float* __restrict__ w, const float* __restrict__ b,
    unsigned short* __restrict__ xn) {
    int wave = threadIdx.x >> 6, lane = threadIdx.x & 63;
    int row = blockIdx.x * 4 + wave;
    size_t base = (size_t)row * D_;
    int off = lane * 4;
    float4 v0 = *(const float4*)&xcur[base + off];
    float4 v1 = *(const float4*)&xcur[base + off + 256];
    float4 v2 = *(const float4*)&xcur[base + off + 512];
    float4 r0 = *(const float4*)&res[base + off];
    float4 r1 = *(const float4*)&res[base + off + 256];
    float4 r2 = *(const float4*)&res[base + off + 512];
    r0.x += v0.x; r0.y += v0.y; r0.z += v0.z; r0.w += v0.w;
    r1.x += v1.x; r1.y += v1.y; r1.z += v1.z; r1.w += v1.w;
    r2.x += v2.x; r2.y += v2.y; r2.z += v2.z; r2.w += v2.w;
    *(float4*)&res[base + off]       = r0;
    *(float4*)&res[base + off + 256] = r1;
    *(float4*)&res[base + off + 512] = r2;
    float s = (v0.x + v0.y + v0.z + v0.w) + (v1.x + v1.y + v1.z + v1.w)
            + (v2.x + v2.y + v2.z + v2.w);
    float mu = wave_sum(s) * (1.0f / D_);
    float4 d0 = make_float4(v0.x - mu, v0.y - mu, v0.z - mu, v0.w - mu);
    float4 d1 = make_float4(v1.x - mu, v1.y - mu, v1.z - mu, v1.w - mu);
    float4 d2 = make_float4(v2.x - mu, v2.y - mu, v2.z - mu, v2.w - mu);
    float sv = d0.x * d0.x + d0.y * d0.y + d0.z * d0.z + d0.w * d0.w
             + d1.x * d1.x + d1.y * d1.y + d1.z * d1.z + d1.w * d1.w
             + d2.x * d2.x + d2.y * d2.y + d2.z * d2.z + d2.w * d2.w;
    float var = wave_sum(sv) * (1.0f / D_);
    float rs = rsqrtf(var + EPS_);
    float4 w0 = *(const float4*)&w[off];
    float4 w1 = *(const float4*)&w[off + 256];
    float4 w2 = *(const float4*)&w[off + 512];
    float4 b0 = *(const float4*)&b[off];
    float4 b1 = *(const float4*)&b[off + 256];
    float4 b2 = *(const float4*)&b[off + 512];
    *(uint2*)&xn[base + off] = (uint2){
        pk2(d0.x * rs * w0.x + b0.x, d0.y * rs * w0.y + b0.y),
        pk2(d0.z * rs * w0.z + b0.z, d0.w * rs * w0.w + b0.w)};
    *(uint2*)&xn[base + off + 256] = (uint2){
        pk2(d1.x * rs * w1.x + b1.x, d1.y * rs * w1.y + b1.y),
        pk2(d1.z * rs * w1.z + b1.z, d1.w * rs * w1.w + b1.w)};
    *(uint2*)&xn[base + off + 512] = (uint2){
        pk2(d2.x * rs * w2.x + b2.x, d2.y * rs * w2.y + b2.y),
        pk2(d2.z * rs * w2.z + b2.z, d2.w * rs * w2.w + b2.w)};
}

// ---------------- final LN: out = LN(xcur + res), wave-per-row --------------
__global__ __launch_bounds__(256) void final_ln_kernel(
    const float* __restrict__ xcur, const float* __restrict__ res,
    const float* __restrict__ w, const float* __restrict__ b,
    float* __restrict__ out) {
    int wave = threadIdx.x >> 6, lane = threadIdx.x & 63;
    int row = blockIdx.x * 4 + wave;
    size_t base = (size_t)row * D_;
    int off = lane * 4;
    float4 v0 = *(const float4*)&xcur[base + off];
    float4 v1 = *(const float4*)&xcur[base + off + 256];
    float4 v2 = *(const float4*)&xcur[base + off + 512];
    float4 r0 = *(const float4*)&res[base + off];
    float4 r1 = *(const float4*)&res[base + off + 256];
    float4 r2 = *(const float4*)&res[base + off + 512];
    v0.x += r0.x; v0.y += r0.y; v0.z += r0.z; v0.w += r0.w;
    v1.x += r1.x; v1.y += r1.y; v1.z += r1.z; v1.w += r1.w;
    v2.x += r2.x; v2.y += r2.y; v2.z += r2.z; v2.w += r2.w;
    float s = (v0.x + v0.y + v0.z + v0.w) + (v1.x + v1.y + v1.z + v1.w)
            + (v2.x + v2.y + v2.z + v2.w);
    float mu = wave_sum(s) * (1.0f / D_);
    float4 d0 = make_float4(v0.x - mu, v0.y - mu, v0.z - mu, v0.w - mu);
    float4 d1 = make_float4(v1.x - mu, v1.y - mu, v1.z - mu, v1.w - mu);
    float4 d2 = make_float4(v2.x - mu, v2.y - mu, v2.z - mu, v2.w - mu);
    float sv = d0.x * d0.x + d0.y * d0.y + d0.z * d0.z + d0.w * d0.w
             + d1.x * d1.x + d1.y * d1.y + d1.z * d1.z + d1.w * d1.w
             + d2.x * d2.x + d2.y * d2.y + d2.z * d2.z + d2.w * d2.w;
    float var = wave_sum(sv) * (1.0f / D_);
    float rs = rsqrtf(var + EPS_);
    float4 w0 = *(const float4*)&w[off];
    float4 w1 = *(const float4*)&w[off + 256];
    float4 w2 = *(const float4*)&w[off + 512];
    float4 b0 = *(const float4*)&b[off];
    float4 b1 = *(const float4*)&b[off + 256];
    float4 b2 = *(const float4*)&b[off + 512];
    *(float4*)&out[base + off] = make_float4(
        d0.x * rs * w0.x + b0.x, d0.y * rs * w0.y + b0.y,
        d0.z * rs * w0.z + b0.z, d0.w * rs * w0.w + b0.w);
    *(float4*)&out[base + off + 256] = make_float4(
        d1.x * rs * w1.x + b1.x, d1.y * rs * w1.y + b1.y,
        d1.z * rs * w1.z + b1.z, d1.w * rs * w1.w + b1.w);
    *(float4*)&out[base + off + 512] = make_float4(
        d2.x * rs * w2.x + b2.x, d2.y * rs * w2.y + b2.y,
        d2.z * rs * w2.z + b2.z, d2.w * rs * w2.w + b2.w);
}

// ---------------- bf16 MFMA GEMM: C[M,N] = A[M,K] * W[N,K]^T ---------------
template <int BM, int BN>
__global__ __launch_bounds__(256) void gemm_bf16_t(
    const unsigned short* __restrict__ A,   // M x K bf16 row-major
    const unsigned short* __restrict__ W,   // N x K bf16 row-major
    float* __restrict__ C, int M, int N, int K) {
    constexpr int FM = BM / 32;
    constexpr int FN = BN / 32;
    constexpr int NLD = (BM + BN) / 64;
    __shared__ unsigned short sA[BM * 32];
    __shared__ unsigned short sW[BN * 32];
    int bm = blockIdx.y * BM, bn = blockIdx.x * BN;
    int tid = threadIdx.x;
    int wave = tid >> 6, lane = tid & 63;
    int wrow = (wave & 1) * (BM / 2), wcol = (wave >> 1) * (BN / 2);
    int quad = lane >> 4, r16 = lane & 15;
    f32x4 acc[FM][FN];
    #pragma unroll
    for (int i = 0; i < FM; i++)
        #pragma unroll
        for (int j = 0; j < FN; j++)
            acc[i][j] = (f32x4){0.f, 0.f, 0.f, 0.f};

    for (int k0 = 0; k0 < K; k0 += 32) {
        #pragma unroll
        for (int r = 0; r < NLD; r++) {
            if (r < BM / 64) {
                int j = r * 256 + tid;
                gload16(&A[(size_t)(bm + (j >> 2)) * K + k0 + (j & 3) * 8],
                        &sA[(r * 256 + wave * 64) * 8]);
            } else {
                int j = (r - BM / 64) * 256 + tid;
                gload16(&W[(size_t)(bn + (j >> 2)) * K + k0 + (j & 3) * 8],
                        &sW[((r - BM / 64) * 256 + wave * 64) * 8]);
            }
        }
        __syncthreads();
        bf16x8 af[FM], wf[FN];
        #pragma unroll
        for (int i = 0; i < FM; i++)
            af[i] = *(const bf16x8*)&sA[(wrow + i * 16 + r16) * 32 + quad * 8];
        #pragma unroll
        for (int j = 0; j < FN; j++)
            wf[j] = *(const bf16x8*)&sW[(wcol + j * 16 + r16) * 32 + quad * 8];
        #pragma unroll
        for (int i = 0; i < FM; i++)
            #pragma unroll
            for (int j = 0; j < FN; j++)
                acc[i][j] = __builtin_amdgcn_mfma_f32_16x16x32_bf16(
                    af[i], wf[j], acc[i][j], 0, 0, 0);
        __syncthreads();
    }
    #pragma unroll
    for (int i = 0; i < FM; i++) {
        #pragma unroll
        for (int j = 0; j < FN; j++) {
            int col = bn + wcol + j * 16 + r16;
            #pragma unroll
            for (int reg = 0; reg < 4; reg++) {
                int row = bm + wrow + i * 16 + quad * 4 + reg;
                C[(size_t)row * N + col] = acc[i][j][reg];
            }
        }
    }
}

// ---------------- dt GEMM bf16 MFMA (M=2048, N=DI, K=64 padded) -------------
__global__ __launch_bounds__(256) void dt_gemm_bf16(
    const unsigned short* __restrict__ A,
    const unsigned short* __restrict__ W,
    const float* __restrict__ bias,
    float* __restrict__ dtb) {
    __shared__ unsigned short sA[128 * 32];
    __shared__ unsigned short sW[128 * 32];
    int bm = blockIdx.y * 128, bn = blockIdx.x * 128;
    int tid = threadIdx.x;
    int wave = tid >> 6, lane = tid & 63;
    int wrow = (wave & 1) * 64, wcol = (wave >> 1) * 64;
    int quad = lane >> 4, r16 = lane & 15;
    f32x4 acc[4][4];
    #pragma unroll
    for (int i = 0; i < 4; i++)
        #pragma unroll
        for (int j = 0; j < 4; j++)
            acc[i][j] = (f32x4){0.f, 0.f, 0.f, 0.f};

    #pragma unroll
    for (int k0 = 0; k0 < KDT_; k0 += 32) {
        #pragma unroll
        for (int r = 0; r < 4; r++) {
            if (r < 2) {
                int j = r * 256 + tid;
                gload16(&A[(size_t)(bm + (j >> 2)) * KDT_ + k0 + (j & 3) * 8],
                        &sA[(r * 256 + wave * 64) * 8]);
            } else {
                int j = (r - 2) * 256 + tid;
                gload16(&W[(size_t)(bn + (j >> 2)) * KDT_ + k0 + (j & 3) * 8],
                        &sW[((r - 2) * 256 + wave * 64) * 8]);
            }
        }
        __syncthreads();
        bf16x8 af[4], wf[4];
        #pragma unroll
        for (int i = 0; i < 4; i++)
            af[i] = *(const bf16x8*)&sA[(wrow + i * 16 + r16) * 32 + quad * 8];
        #pragma unroll
        for (int j = 0; j < 4; j++)
            wf[j] = *(const bf16x8*)&sW[(wcol + j * 16 + r16) * 32 + quad * 8];
        #pragma unroll
        for (int i = 0; i < 4; i++)
            #pragma unroll
            for (int j = 0; j < 4; j++)
                acc[i][j] = __builtin_amdgcn_mfma_f32_16x16x32_bf16(
                    af[i], wf[j], acc[i][j], 0, 0, 0);
        __syncthreads();
    }
    #pragma unroll
    for (int i = 0; i < 4; i++) {
        #pragma unroll
        for (int j = 0; j < 4; j++) {
            int col = bn + wcol + j * 16 + r16;
            float bv = bias[col];
            #pragma unroll
            for (int reg = 0; reg < 4; reg++) {
                int row = bm + wrow + i * 16 + quad * 4 + reg;
                float v = acc[i][j][reg] + bv;
                v = (v > 20.f) ? v : log1pf(__expf(v));
                dtb[(size_t)row * DI_ + col] = v;
            }
        }
    }
}

// ---------------- fused conv+SiLU+x_proj GEMM (split-K over ks) -------------
__global__ __launch_bounds__(256) void conv_xproj_kernel(
    const float* __restrict__ xz,
    const float* __restrict__ cw,
    const float* __restrict__ cb,
    const unsigned short* __restrict__ W,
    float* __restrict__ xcf,
    float* __restrict__ Pb) {
    __shared__ float sxz[67 * 96];
    __shared__ unsigned short sxcb[64 * 104];
    __shared__ float scw[96 * 4];
    __shared__ float scb[96];
    unsigned short* sW = (unsigned short*)sxz;

    int ks = blockIdx.x;
    int bm = blockIdx.y * 64;
    int tid = threadIdx.x;
    int b = bm >> 10, t0 = bm & (L_ - 1);
    int dbase = ks * KCH_;

    if (tid < 96) {
        int d = dbase + tid;
        *(float4*)&scw[tid * 4] = *(const float4*)&cw[d * 4];
        scb[tid] = cb[d];
    }
    for (int j = tid; j < 67 * 24; j += 256) {
        int r = j / 24, c4 = (j % 24) * 4;
        int tt = t0 + r - 3;
        float4 v = make_float4(0.f, 0.f, 0.f, 0.f);
        if (tt >= 0)
            v = *(const float4*)&xz[((size_t)(b * L_ + tt)) * (2 * DI_) + dbase + c4];
        *(float4*)&sxz[r * 96 + c4] = v;
    }
    __syncthreads();
    for (int j = tid; j < 64 * 96; j += 256) {
        int r = j / 96, c = j % 96;
        float acc = scb[c];
        #pragma unroll
        for (int k = 0; k < KC_; k++)
            acc = fmaf(scw[c * 4 + k], sxz[(r + k) * 96 + c], acc);
        float v = acc / (1.0f + __expf(-acc));
        xcf[(size_t)(bm + r) * DI_ + dbase + c] = v;
        sxcb[r * 104 + c] = f2bf(v);
    }
    __syncthreads();
    for (int j = tid; j < 80 * 12; j += 256) {
        int row = j / 12, c16 = (j % 12) * 8;
        *(uint4*)&sW[row * 104 + c16] =
            *(const uint4*)&W[(size_t)row * DI_ + dbase + c16];
    }
    __syncthreads();
    int wave = tid >> 6, lane = tid & 63;
    int quad = lane >> 4, r16 = lane & 15;
    f32x4 acc[5];
    #pragma unroll
    for (int j = 0; j < 5; j++) acc[j] = (f32x4){0.f, 0.f, 0.f, 0.f};
    #pragma unroll
    for (int kk = 0; kk < 3; kk++) {
        bf16x8 af = *(const bf16x8*)&sxcb[(wave * 16 + r16) * 104 + kk * 32 + quad * 8];
        #pragma unroll
        for (int j = 0; j < 5; j++) {
            bf16x8 wf = *(const bf16x8*)&sW[(j * 16 + r16) * 104 + kk * 32 + quad * 8];
            acc[j] = __builtin_amdgcn_mfma_f32_16x16x32_bf16(af, wf, acc[j], 0, 0, 0);
        }
    }
    #pragma unroll
    for (int j = 0; j < 5; j++) {
        int col = j * 16 + r16;
        #pragma unroll
        for (int reg = 0; reg < 4; reg++) {
            int row = bm + wave * 16 + quad * 4 + reg;
            Pb[((size_t)ks * M_ + row) * 80 + col] = acc[j][reg];
        }
    }
}

// reduce split-K partials; scatter into dbc_bf (M x 64 bf16) and packed BC
__global__ void xproj_reduce_kernel(const float* __restrict__ Pb,
                                    unsigned short* __restrict__ dbc_bf,
                                    float* __restrict__ bcp) {
    int i = blockIdx.x * 256 + threadIdx.x;   // over M_*80
    float s = 0.f;
    #pragma unroll
    for (int ks = 0; ks < KS_; ks++) s += Pb[(size_t)ks * (M_ * 80) + i];
    int m = i / 80, col = i % 80;
    if (col < DR_) {
        dbc_bf[m * KDT_ + col] = f2bf(s);
    } else if (col < DR_ + NS_) {
        bcp[m * 32 + 2 * (col - DR_)] = s;         // B_n
    } else {
        bcp[m * 32 + 2 * (col - DR_ - NS_) + 1] = s; // C_n
    }
}

// ---------------- scan pass A: per-chunk summaries (S[16] + sd scalar) ------
// 128-thread blocks, grid = B*NC*(DI/128) = 768 (3/CU even).
__global__ __launch_bounds__(128) void scan_ps_kernel(
    const float* __restrict__ dtb,
    const float* __restrict__ xcf,
    const float4* __restrict__ bcp4,
    const float* __restrict__ negA,
    float* __restrict__ Sb,
    float* __restrict__ sdb) {
    const int NDB = DI_ / 128;         // 12 d-blocks
    int bx = blockIdx.x;
    int dblk = bx % NDB;
    int c = (bx / NDB) % NC_;
    int b = bx / (NDB * NC_);
    int d = dblk * 128 + threadIdx.x;

    float A[NS_];
    #pragma unroll
    for (int n = 0; n < NS_; n++) A[n] = negA[(size_t)d * NS_ + n];
    float h[NS_];
    #pragma unroll
    for (int n = 0; n < NS_; n++) h[n] = 0.f;
    float sd = 0.f;

    size_t btbase = (size_t)(b * L_ + c * T_);
    const float* pdt = dtb + btbase * DI_ + d;
    const float* pxc = xcf + btbase * DI_ + d;
    const float4* pbc = bcp4 + btbase * 8;

    #pragma unroll 4
    for (int t = 0; t < T_; t++) {
        float dt = pdt[(size_t)t * DI_];
        float u  = dt * pxc[(size_t)t * DI_];
        sd += dt;
        #pragma unroll
        for (int q = 0; q < 8; q++) {
            float4 v = pbc[t * 8 + q];
            float e0 = __expf(dt * A[2 * q]);
            h[2 * q] = fmaf(e0, h[2 * q], u * v.x);
            float e1 = __expf(dt * A[2 * q + 1]);
            h[2 * q + 1] = fmaf(e1, h[2 * q + 1], u * v.z);
        }
    }

    size_t o = (((size_t)b * NC_ + c) * DI_ + d) * NS_;
    #pragma unroll
    for (int n = 0; n < NS_; n++) Sb[o + n] = h[n];
    sdb[((size_t)b * NC_ + c) * DI_ + d] = sd;
}

// ---------------- scan pass B: sequential combine, 4-deep pipeline ----------
__global__ __launch_bounds__(64) void scan_combine_kernel(
    const float* __restrict__ Sb, const float* __restrict__ sdb,
    const float* __restrict__ negA, float* __restrict__ hin) {
    int i = blockIdx.x * 64 + threadIdx.x;    // over B*DI*NS
    int b = i / (DI_ * NS_);
    int rem = i % (DI_ * NS_);
    int d = rem >> 4;                          // NS = 16
    float Aa = negA[rem];
    const size_t str = (size_t)DI_ * NS_;
    size_t o = (size_t)b * NC_ * str + rem;
    size_t osd = (size_t)b * NC_ * DI_ + d;
    float h = 0.f;
    float s0 = Sb[o],           sd0 = sdb[osd];
    float s1 = Sb[o + str],     sd1 = sdb[osd + DI_];
    float s2 = Sb[o + 2 * str], sd2 = sdb[osd + 2 * DI_];
    float s3 = Sb[o + 3 * str], sd3 = sdb[osd + 3 * DI_];
    for (int c = 0; c < NC_ - 4; c += 4) {
        float n0 = Sb[o + 4 * str], nd0 = sdb[osd + 4 * DI_];
        float n1 = Sb[o + 5 * str], nd1 = sdb[osd + 5 * DI_];
        float n2 = Sb[o + 6 * str], nd2 = sdb[osd + 6 * DI_];
        float n3 = Sb[o + 7 * str], nd3 = sdb[osd + 7 * DI_];
        hin[o] = h;           h = fmaf(__expf(Aa * sd0), h, s0);
        hin[o + str] = h;     h = fmaf(__expf(Aa * sd1), h, s1);
        hin[o + 2 * str] = h; h = fmaf(__expf(Aa * sd2), h, s2);
        hin[o + 3 * str] = h; h = fmaf(__expf(Aa * sd3), h, s3);
        s0 = n0; sd0 = nd0; s1 = n1; sd1 = nd1;
        s2 = n2; sd2 = nd2; s3 = n3; sd3 = nd3;
        o += 4 * str; osd += 4 * DI_;
    }
    hin[o] = h;           h = fmaf(__expf(Aa * sd0), h, s0);
    hin[o + str] = h;     h = fmaf(__expf(Aa * sd1), h, s1);
    hin[o + 2 * str] = h; h = fmaf(__expf(Aa * sd2), h, s2);
    hin[o + 3 * str] = h;
}

// ---------------- scan pass C: exact recurrence from hin -> yg --------------
// 128-thread blocks, grid = 768 (3/CU even).
__global__ __launch_bounds__(128) void scan_out_kernel(
    const float* __restrict__ dtb, const float* __restrict__ xcf,
    const float4* __restrict__ bcp4, const float* __restrict__ negA,
    const float* __restrict__ hin, const float* __restrict__ xz,
    const float* __restrict__ Dp, unsigned short* __restrict__ yg) {
    const int NDB = DI_ / 128;
    int bx = blockIdx.x;
    int dblk = bx % NDB;
    int c = (bx / NDB) % NC_;
    int b = bx / (NDB * NC_);
    int d = dblk * 128 + threadIdx.x;

    float A[NS_];
    #pragma unroll
    for (int n = 0; n < NS_; n++) A[n] = negA[(size_t)d * NS_ + n];
    size_t o = (((size_t)b * NC_ + c) * DI_ + d) * NS_;
    float h[NS_];
    #pragma unroll
    for (int n = 0; n < NS_; n++) h[n] = hin[o + n];
    float dpv = Dp[d];

    size_t btbase = (size_t)(b * L_ + c * T_);
    const float* pdt = dtb + btbase * DI_ + d;
    const float* pxc = xcf + btbase * DI_ + d;
    const float4* pbc = bcp4 + btbase * 8;

    #pragma unroll 4
    for (int t = 0; t < T_; t++) {
        float dt = pdt[(size_t)t * DI_];
        float xc = pxc[(size_t)t * DI_];
        float u = dt * xc;
        float y = 0.f;
        #pragma unroll
        for (int q = 0; q < 8; q++) {
            float4 v = pbc[t * 8 + q];
            float e0 = __expf(dt * A[2 * q]);
            h[2 * q] = fmaf(e0, h[2 * q], u * v.x);
            y = fmaf(v.y, h[2 * q], y);
            float e1 = __expf(dt * A[2 * q + 1]);
            h[2 * q + 1] = fmaf(e1, h[2 * q + 1], u * v.z);
            y = fmaf(v.w, h[2 * q + 1], y);
        }
        size_t row = btbase + t;
        float zv = xz[row * (2 * DI_) + DI_ + d];
        float yy = y + xc * dpv;
        yy *= zv / (1.0f + __expf(-zv));
        yg[row * DI_ + d] = f2bf(yy);
    }
}

extern "C" void kernel_launch(void* const* d_in, const int* in_sizes, int n_in,
                              void* d_out, int out_size, void* d_ws, size_t ws_size,
                              hipStream_t stream) {
    const float* x        = (const float*)d_in[0];
    const float* ln_w     = (const float*)d_in[1];
    const float* ln_b     = (const float*)d_in[2];
    const float* in_proj  = (const float*)d_in[3];
    const float* conv_w   = (const float*)d_in[4];
    const float* conv_b   = (const float*)d_in[5];
    const float* x_proj   = (const float*)d_in[6];
    const float* dt_w     = (const float*)d_in[7];
    const float* dt_b     = (const float*)d_in[8];
    const float* A_log    = (const float*)d_in[9];
    const float* D_skip   = (const float*)d_in[10];
    const float* out_proj = (const float*)d_in[11];
    const float* fn_w     = (const float*)d_in[12];
    const float* fn_b     = (const float*)d_in[13];
    float* out = (float*)d_out;

    char* p = (char*)d_ws;
    auto alloc = [&](size_t bytes) {
        char* r = p;
        p += (bytes + 255) & ~(size_t)255;
        return (void*)r;
    };
    float* xcur = (float*)alloc((size_t)M_ * D_ * 4);
    float* res  = (float*)alloc((size_t)M_ * D_ * 4);
    unsigned short* xn = (unsigned short*)alloc((size_t)M_ * D_ * 2);
    float* xz   = (float*)alloc((size_t)M_ * 2 * DI_ * 4);
    float* dtb  = (float*)alloc((size_t)M_ * DI_ * 4);
    float* xcf  = (float*)alloc((size_t)M_ * DI_ * 4);
    unsigned short* dbc_bf = (unsigned short*)alloc((size_t)M_ * KDT_ * 2);
    float* bcp  = (float*)alloc((size_t)M_ * 32 * 4);
    unsigned short* yg = (unsigned short*)alloc((size_t)M_ * DI_ * 2);
    float* Sb   = (float*)alloc((size_t)B_ * NC_ * DI_ * NS_ * 4);   // 6.3 MB
    float* sdb  = (float*)alloc((size_t)B_ * NC_ * DI_ * 4);         // 0.4 MB
    float* hin  = (float*)alloc((size_t)B_ * NC_ * DI_ * NS_ * 4);
    float* Pb   = (float*)alloc((size_t)KS_ * M_ * 80 * 4);
    float* negA = (float*)alloc((size_t)NL_ * DI_ * NS_ * 4);
    const size_t n_wi = (size_t)NL_ * 2 * DI_ * D_;
    const size_t n_wo = (size_t)NL_ * D_ * DI_;
    const size_t n_wx = (size_t)NL_ * 80 * DI_;
    const size_t n_wdt = (size_t)NL_ * DI_ * KDT_;
    unsigned short* wi_bf = (unsigned short*)alloc(n_wi * 2);
    unsigned short* wo_bf = (unsigned short*)alloc(n_wo * 2);
    unsigned short* wx_bf = (unsigned short*)alloc(n_wx * 2);
    unsigned short* wdt_bf = (unsigned short*)alloc(n_wdt * 2);

    prep_kernel<<<7808, 256, 0, stream>>>(
        in_proj, wi_bf, out_proj, wo_bf, x_proj, wx_bf,
        dt_w, wdt_bf, A_log, negA, x, xcur, res, dbc_bf);

    for (int l = 0; l < NL_; l++) {
        const float* negA_l = negA + (size_t)l * DI_ * NS_;

        ln_res_kernel<<<M_ / 4, 256, 0, stream>>>(
            xcur, res, ln_w + l * D_, ln_b + l * D_, xn);

        // xz = xn @ Wi^T  (M=2048, N=3072, K=768): 128x64 -> 768 blocks (3/CU)
        gemm_bf16_t<128, 64><<<dim3((2 * DI_) / 64, M_ / 128), 256, 0, stream>>>(
            xn, wi_bf + (size_t)l * 2 * DI_ * D_, xz, M_, 2 * DI_, D_);

        conv_xproj_kernel<<<dim3(KS_, M_ / 64), 256, 0, stream>>>(
            xz, conv_w + l * DI_ * KC_, conv_b + l * DI_,
            wx_bf + (size_t)l * 80 * DI_, xcf, Pb);
        xproj_reduce_kernel<<<(M_ * 80) / 256, 256, 0, stream>>>(Pb, dbc_bf, bcp);

        dt_gemm_bf16<<<dim3(DI_ / 128, M_ / 128), 256, 0, stream>>>(
            dbc_bf, wdt_bf + (size_t)l * DI_ * KDT_, dt_b + l * DI_, dtb);

        scan_ps_kernel<<<B_ * NC_ * (DI_ / 128), 128, 0, stream>>>(
            dtb, xcf, (const float4*)bcp, negA_l, Sb, sdb);
        scan_combine_kernel<<<(B_ * DI_ * NS_) / 64, 64, 0, stream>>>(
            Sb, sdb, negA_l, hin);
        scan_out_kernel<<<B_ * NC_ * (DI_ / 128), 128, 0, stream>>>(
            dtb, xcf, (const float4*)bcp, negA_l, hin, xz,
            D_skip + (size_t)l * DI_, yg);

        // xcur = yg @ Wo^T  (M=2048, N=768, K=1536): 64x64 -> 384 blocks
        gemm_bf16_t<64, 64><<<dim3(D_ / 64, M_ / 64), 256, 0, stream>>>(
            yg, wo_bf + (size_t)l * D_ * DI_, xcur, M_, D_, DI_);
    }

    final_ln_kernel<<<M_ / 4, 256, 0, stream>>>(xcur, res, fn_w, fn_b, out);
}